// Round 8
// baseline (2335.774 us; speedup 1.0000x reference)
//
#include <hip/hip_runtime.h>

#define N_NODES 100000
#define NLAYERS 4
#define NPROP 2
#define NGRAPHS 50
#define NE_MAIN 400000
#define NE_SET 300000
#define NSETS 9            // 0=main, 1..4=inner, 5..8=fwd
#define CSR_TOTAL (NE_MAIN + 8 * NE_SET)
#define ASTR 296           // LDS agg row stride (shorts)

typedef __attribute__((ext_vector_type(8))) short bf8_t;  // 8 bf16 (4 VGPRs)
typedef __attribute__((ext_vector_type(4))) float f4_t;

// ---------------- static device scratch ----------------
// x / pi / fs-copy stored as bf16 (2 B/elem) — halves all activation traffic.
__device__ __align__(16) unsigned short g_x[(size_t)N_NODES * 256];
__device__ __align__(16) unsigned short g_pi[(size_t)N_NODES * 256];
__device__ __align__(16) unsigned short g_fsb[(size_t)N_NODES * 32];
__device__ __align__(16) float g_agg16[(size_t)N_NODES * 16];
__device__ __align__(16) float g_dinv[NSETS * N_NODES];
__device__ __align__(16) float g_pooled[NGRAPHS * 256];
__device__ __align__(16) unsigned short g_WinhT[288 * 256];  // W_in^T hi [n][k]
__device__ __align__(16) unsigned short g_WinlT[288 * 256];
__device__ __align__(16) unsigned short g_WfwhT[288 * 256];
__device__ __align__(16) unsigned short g_WfwlT[288 * 256];
__device__ int g_deg[NSETS * N_NODES];
__device__ int g_cur[NSETS * N_NODES];
__device__ int g_off[NSETS * (N_NODES + 1)];
__device__ __align__(8) int2 g_csr[CSR_TOTAL];   // {src, float_bits(nrm)}
__device__ int g_cnt[4];
__device__ int g_lists[NLAYERS * N_NODES];

__host__ __device__ inline int csr_base(int slot) {
    return slot == 0 ? 0 : NE_MAIN + (slot - 1) * NE_SET;
}

__device__ inline unsigned short f2bf(float f) {  // RNE fp32 -> bf16
    unsigned u = __float_as_uint(f);
    return (unsigned short)((u + 0x7fffu + ((u >> 16) & 1u)) >> 16);
}
__device__ inline float bf2f(unsigned short b) {
    return __uint_as_float(((unsigned)b) << 16);
}
__device__ inline float4 ldbf4(const unsigned short* p) {
    ushort4 u = *(const ushort4*)p;
    float4 f;
    f.x = bf2f(u.x); f.y = bf2f(u.y); f.z = bf2f(u.z); f.w = bf2f(u.w);
    return f;
}

// decompose linear edge id over [main | inner0..3 | fwd0..3]
__device__ inline void edge_decode(int t, const int* ei, const int* inner, const int* fwd,
                                   int& slot, const int*& es, const int*& ed, int& e) {
    if (t < NE_MAIN) {
        slot = 0; e = t; es = ei; ed = ei + NE_MAIN;
    } else {
        int r = t - NE_MAIN;
        int grp = r / NE_SET;          // 0..7
        e = r - grp * NE_SET;
        slot = 1 + grp;                // 1..4 inner, 5..8 fwd
        const int* base = (grp < 4) ? (inner + grp * 2 * NE_SET)
                                    : (fwd + (grp - 4) * 2 * NE_SET);
        es = base; ed = base + NE_SET;
    }
}

// ----------------------------- setup -----------------------------

__global__ __launch_bounds__(256) void k_init() {
    int i = blockIdx.x * blockDim.x + threadIdx.x;
    if (i < NSETS * N_NODES) g_deg[i] = 0;
    if (i < NGRAPHS * 256) g_pooled[i] = 0.f;
    if (i < 4) g_cnt[i] = 0;
}

__global__ __launch_bounds__(256) void k_fsb(const float* __restrict__ fs) {
    int i = blockIdx.x * blockDim.x + threadIdx.x;
    if (i < N_NODES * 32) g_fsb[i] = f2bf(fs[i]);
}

__global__ __launch_bounds__(256) void k_count_all(const int* __restrict__ ei,
                                                   const int* __restrict__ inner,
                                                   const int* __restrict__ fwd) {
    int t = blockIdx.x * blockDim.x + threadIdx.x;
    if (t >= CSR_TOTAL) return;
    int slot, e; const int *es, *ed;
    edge_decode(t, ei, inner, fwd, slot, es, ed, e);
    atomicAdd(&g_deg[slot * N_NODES + ed[e]], 1);
}

__global__ __launch_bounds__(256) void k_dinv() {
    int i = blockIdx.x * blockDim.x + threadIdx.x;
    if (i < NSETS * N_NODES) g_dinv[i] = rsqrtf(1.0f + (float)g_deg[i]);
}

// split W into bf16 hi/lo, transposed to [n][k]; which: 0=W_in, 1=W_fw
__global__ __launch_bounds__(256) void k_wt(const float* __restrict__ W, int which) {
    int t = blockIdx.x * blockDim.x + threadIdx.x;  // over 288*256
    if (t >= 288 * 256) return;
    unsigned short* WhT = which ? g_WfwhT : g_WinhT;
    unsigned short* WlT = which ? g_WfwlT : g_WinlT;
    int k = t >> 8, n = t & 255;
    float w = W[t];
    unsigned short h = f2bf(w);
    unsigned short l = f2bf(w - bf2f(h));
    WhT[n * 288 + k] = h;
    WlT[n * 288 + k] = l;
}

#define SCAN_T 1024
#define SCAN_SEQ 8
__global__ __launch_bounds__(SCAN_T) void k_scan() {  // one block per set; seeds g_cur=off
    int set = blockIdx.x;
    const int* deg = g_deg + (size_t)set * N_NODES;
    int* off = g_off + (size_t)set * (N_NODES + 1);
    int* cur = g_cur + (size_t)set * N_NODES;
    __shared__ int sm[SCAN_T];
    __shared__ int s_carry;
    int t = threadIdx.x;
    if (t == 0) s_carry = 0;
    __syncthreads();
    for (int base = 0; base < N_NODES; base += SCAN_T * SCAN_SEQ) {
        int v[SCAN_SEQ];
        int sum = 0;
        int idx0 = base + t * SCAN_SEQ;
#pragma unroll
        for (int j = 0; j < SCAN_SEQ; j++) {
            int id = idx0 + j;
            v[j] = (id < N_NODES) ? deg[id] : 0;
            sum += v[j];
        }
        sm[t] = sum;
        __syncthreads();
        for (int o = 1; o < SCAN_T; o <<= 1) {
            int u = (t >= o) ? sm[t - o] : 0;
            __syncthreads();
            sm[t] += u;
            __syncthreads();
        }
        int total = sm[SCAN_T - 1];
        int run = s_carry + sm[t] - sum;
#pragma unroll
        for (int j = 0; j < SCAN_SEQ; j++) {
            int id = idx0 + j;
            if (id < N_NODES) { off[id] = run; cur[id] = run; }
            run += v[j];
        }
        __syncthreads();
        if (t == 0) s_carry += total;
        __syncthreads();
    }
    if (t == 0) off[N_NODES] = s_carry;
}

__global__ __launch_bounds__(256) void k_fill_all(const int* __restrict__ ei,
                                                  const int* __restrict__ inner,
                                                  const int* __restrict__ fwd) {
    int t = blockIdx.x * blockDim.x + threadIdx.x;
    if (t >= CSR_TOTAL) return;
    int slot, e; const int *es, *ed;
    edge_decode(t, ei, inner, fwd, slot, es, ed, e);
    int s = es[e], d = ed[e];
    int pos = atomicAdd(&g_cur[slot * N_NODES + d], 1);   // absolute slot
    float nrm = g_dinv[slot * N_NODES + s] * g_dinv[slot * N_NODES + d];
    g_csr[csr_base(slot) + pos] = make_int2(s, __float_as_int(nrm));
}

// block-local histogram -> 4 global atomics per block
__global__ __launch_bounds__(256) void k_lists(const int* __restrict__ layers) {
    __shared__ int lcnt[4];
    __shared__ int lbase[4];
    int i = blockIdx.x * blockDim.x + threadIdx.x;
    if (threadIdx.x < 4) lcnt[threadIdx.x] = 0;
    __syncthreads();
    int l = -1, p = 0;
    if (i < N_NODES) {
        l = layers[i];
        p = atomicAdd(&lcnt[l], 1);
    }
    __syncthreads();
    if (threadIdx.x < 4) lbase[threadIdx.x] = atomicAdd(&g_cnt[threadIdx.x], lcnt[threadIdx.x]);
    __syncthreads();
    if (l >= 0) g_lists[l * N_NODES + lbase[l] + p] = i;
}

// ----------------------------- conv0 (K=16) -----------------------------

__global__ __launch_bounds__(256) void k_gather16(const float* __restrict__ xin) {
    int g = blockIdx.x * blockDim.x + threadIdx.x;
    int i = g >> 4, lane = g & 15;
    if (i >= N_NODES) return;
    float dv = g_dinv[i];
    float acc = dv * dv * xin[i * 16 + lane];
    int e0 = g_off[i], e1 = g_off[i + 1];
    for (int e = e0; e < e1; e++) {
        int2 sn = g_csr[e];
        acc += __int_as_float(sn.y) * xin[sn.x * 16 + lane];
    }
    g_agg16[i * 16 + lane] = acc;
}

__global__ __launch_bounds__(256) void k_gemm0(const float* __restrict__ W,
                                               const float* __restrict__ bias) {
    __shared__ float a[128];
    int base = blockIdx.x * 8;
    int t = threadIdx.x;
    if (t < 128) a[t] = g_agg16[base * 16 + t];
    __syncthreads();
    float bb = bias[t];
    for (int r = 0; r < 8; r++) {
        float acc = bb;
#pragma unroll
        for (int k = 0; k < 16; k++) acc += a[r * 16 + k] * W[k * 256 + t];
        g_x[(size_t)(base + r) * 256 + t] = f2bf(acc);
    }
}

// -------- fused conv: bf16 CSR gather -> LDS (hi/lo) -> 3-term MFMA GEMM --------
// block: 16 rows x 256 cols, 4 waves, 8 blocks/CU (LDS 19 KB).
// Phase 1: wave w gathers rows w*4..w*4+3 (2-way unrolled edge loop).
// Phase 2: wave w computes col stripe w*64..w*64+63 for all 16 rows.

__global__ __launch_bounds__(256, 8) void k_conv(int slot, int which,
                                                 const float* __restrict__ bias,
                                                 int layer, int topi) {
    int count = (layer >= 0) ? g_cnt[layer] : N_NODES;
    int base = blockIdx.x * 16;
    if (base >= count) return;
    const unsigned short* WhT = which ? g_WfwhT : g_WinhT;
    const unsigned short* WlT = which ? g_WfwlT : g_WinlT;
    unsigned short* out = topi ? g_pi : g_x;

    __shared__ unsigned short lds_h[16 * ASTR];
    __shared__ unsigned short lds_l[16 * ASTR];
    __shared__ int rows_s[16];
    int t = threadIdx.x;
    if (t < 16) {
        int r = base + t;
        rows_s[t] = (r < count) ? ((layer >= 0) ? g_lists[layer * N_NODES + r] : r) : -1;
    }
    __syncthreads();

    int wv = t >> 6, lane = t & 63;

    // ---- phase 1: gather 4 rows per wave into LDS ----
    const int* offp = g_off + (size_t)slot * (N_NODES + 1);
    int cb = csr_base(slot);
    for (int rr = 0; rr < 4; rr++) {
        int lr = wv * 4 + rr;
        int row = rows_s[lr];
        float4 acc = {0.f, 0.f, 0.f, 0.f};
        float4 accb = {0.f, 0.f, 0.f, 0.f};
        float4 accs = {0.f, 0.f, 0.f, 0.f};
        float4 accsb = {0.f, 0.f, 0.f, 0.f};
        if (row >= 0) {
            float dv = g_dinv[(size_t)slot * N_NODES + row];
            float d2 = dv * dv;
            acc = ldbf4(&g_x[(size_t)row * 256 + lane * 4]);
            acc.x *= d2; acc.y *= d2; acc.z *= d2; acc.w *= d2;
            if (lane < 8) {
                accs = ldbf4(&g_fsb[(size_t)row * 32 + lane * 4]);
                accs.x *= d2; accs.y *= d2; accs.z *= d2; accs.w *= d2;
            }
            int e0 = offp[row] + cb, e1 = offp[row + 1] + cb;
            int e = e0;
            for (; e + 1 < e1; e += 2) {   // 2 independent chains -> better MLP
                int2 sa = g_csr[e];
                int2 sb = g_csr[e + 1];
                float na = __int_as_float(sa.y);
                float nb = __int_as_float(sb.y);
                float4 va = ldbf4(&g_x[(size_t)sa.x * 256 + lane * 4]);
                float4 vb = ldbf4(&g_x[(size_t)sb.x * 256 + lane * 4]);
                acc.x += na * va.x; acc.y += na * va.y;
                acc.z += na * va.z; acc.w += na * va.w;
                accb.x += nb * vb.x; accb.y += nb * vb.y;
                accb.z += nb * vb.z; accb.w += nb * vb.w;
                if (lane < 8) {
                    float4 fa = ldbf4(&g_fsb[(size_t)sa.x * 32 + lane * 4]);
                    float4 fb = ldbf4(&g_fsb[(size_t)sb.x * 32 + lane * 4]);
                    accs.x += na * fa.x; accs.y += na * fa.y;
                    accs.z += na * fa.z; accs.w += na * fa.w;
                    accsb.x += nb * fb.x; accsb.y += nb * fb.y;
                    accsb.z += nb * fb.z; accsb.w += nb * fb.w;
                }
            }
            if (e < e1) {
                int2 sa = g_csr[e];
                float na = __int_as_float(sa.y);
                float4 va = ldbf4(&g_x[(size_t)sa.x * 256 + lane * 4]);
                acc.x += na * va.x; acc.y += na * va.y;
                acc.z += na * va.z; acc.w += na * va.w;
                if (lane < 8) {
                    float4 fa = ldbf4(&g_fsb[(size_t)sa.x * 32 + lane * 4]);
                    accs.x += na * fa.x; accs.y += na * fa.y;
                    accs.z += na * fa.z; accs.w += na * fa.w;
                }
            }
            acc.x += accb.x; acc.y += accb.y; acc.z += accb.z; acc.w += accb.w;
            accs.x += accsb.x; accs.y += accsb.y; accs.z += accsb.z; accs.w += accsb.w;
        }
        ushort4 h, l;
        h.x = f2bf(acc.x); l.x = f2bf(acc.x - bf2f(h.x));
        h.y = f2bf(acc.y); l.y = f2bf(acc.y - bf2f(h.y));
        h.z = f2bf(acc.z); l.z = f2bf(acc.z - bf2f(h.z));
        h.w = f2bf(acc.w); l.w = f2bf(acc.w - bf2f(h.w));
        *(ushort4*)&lds_h[lr * ASTR + lane * 4] = h;
        *(ushort4*)&lds_l[lr * ASTR + lane * 4] = l;
        if (lane < 8) {
            ushort4 hs, ls;
            hs.x = f2bf(accs.x); ls.x = f2bf(accs.x - bf2f(hs.x));
            hs.y = f2bf(accs.y); ls.y = f2bf(accs.y - bf2f(hs.y));
            hs.z = f2bf(accs.z); ls.z = f2bf(accs.z - bf2f(hs.z));
            hs.w = f2bf(accs.w); ls.w = f2bf(accs.w - bf2f(hs.w));
            *(ushort4*)&lds_h[lr * ASTR + 256 + lane * 4] = hs;
            *(ushort4*)&lds_l[lr * ASTR + 256 + lane * 4] = ls;
        }
    }
    __syncthreads();

    // ---- phase 2: MFMA (16 rows x 64 cols per wave) ----
    int m = lane & 15, quad = lane >> 4;
    int n0 = wv * 64;
    f4_t acc2[4];
#pragma unroll
    for (int ct = 0; ct < 4; ct++) acc2[ct] = (f4_t){0.f, 0.f, 0.f, 0.f};

    for (int k0 = 0; k0 < 288; k0 += 32) {
        bf8_t ah = *(const bf8_t*)&lds_h[m * ASTR + k0 + quad * 8];
        bf8_t al = *(const bf8_t*)&lds_l[m * ASTR + k0 + quad * 8];
#pragma unroll
        for (int ct = 0; ct < 4; ct++) {
            int n = n0 + ct * 16 + m;
            bf8_t bh = *(const bf8_t*)&WhT[(size_t)n * 288 + k0 + quad * 8];
            bf8_t bl = *(const bf8_t*)&WlT[(size_t)n * 288 + k0 + quad * 8];
            acc2[ct] = __builtin_amdgcn_mfma_f32_16x16x32_bf16(ah, bh, acc2[ct], 0, 0, 0);
            acc2[ct] = __builtin_amdgcn_mfma_f32_16x16x32_bf16(al, bh, acc2[ct], 0, 0, 0);
            acc2[ct] = __builtin_amdgcn_mfma_f32_16x16x32_bf16(ah, bl, acc2[ct], 0, 0, 0);
        }
    }
    // epilogue: C/D layout col=lane&15, row=quad*4+reg
#pragma unroll
    for (int r = 0; r < 4; r++) {
        int row = rows_s[quad * 4 + r];
        if (row < 0) continue;
#pragma unroll
        for (int ct = 0; ct < 4; ct++) {
            int n = n0 + ct * 16 + m;
            out[(size_t)row * 256 + n] = f2bf(acc2[ct][r] + bias[n]);
        }
    }
}

// ----------------------------- misc -----------------------------

// half-wave (32 lanes) per row, uint4 = 16 B per lane
__global__ __launch_bounds__(256) void k_copy_rows(int layer) {
    int w = (blockIdx.x * blockDim.x + threadIdx.x) >> 5;
    int lane = threadIdx.x & 31;
    if (w >= g_cnt[layer]) return;
    int i = g_lists[layer * N_NODES + w];
    *(uint4*)(g_x + (size_t)i * 256 + lane * 8) =
        *(const uint4*)(g_pi + (size_t)i * 256 + lane * 8);
}

__global__ __launch_bounds__(256) void k_relu() {
    int i = blockIdx.x * blockDim.x + threadIdx.x;  // over N*256/8
    if (i >= N_NODES * 32) return;
    ushort4 a = ((ushort4*)g_x)[i * 2];
    ushort4 b = ((ushort4*)g_x)[i * 2 + 1];
    a.x = (a.x & 0x8000) ? 0 : a.x; a.y = (a.y & 0x8000) ? 0 : a.y;
    a.z = (a.z & 0x8000) ? 0 : a.z; a.w = (a.w & 0x8000) ? 0 : a.w;
    b.x = (b.x & 0x8000) ? 0 : b.x; b.y = (b.y & 0x8000) ? 0 : b.y;
    b.z = (b.z & 0x8000) ? 0 : b.z; b.w = (b.w & 0x8000) ? 0 : b.w;
    ((ushort4*)g_x)[i * 2] = a;
    ((ushort4*)g_x)[i * 2 + 1] = b;
}

__global__ __launch_bounds__(256) void k_pool(const int* __restrict__ batch) {
    __shared__ int bs[128];
    int i0 = blockIdx.x * 128;
    if (threadIdx.x < 128) {
        int i = i0 + threadIdx.x;
        bs[threadIdx.x] = (i < N_NODES) ? batch[i] : -1;
    }
    __syncthreads();
    int c = threadIdx.x;
    int lim = min(128, N_NODES - i0);
    float acc = 0.f;
    int cur = bs[0];
    for (int ii = 0; ii < lim; ii++) {
        int g = bs[ii];
        if (g != cur) { atomicAdd(&g_pooled[cur * 256 + c], acc); acc = 0.f; cur = g; }
        acc += bf2f(g_x[(size_t)(i0 + ii) * 256 + c]);
    }
    atomicAdd(&g_pooled[cur * 256 + c], acc);
}

__global__ void k_final(const float* __restrict__ W_lin, const float* __restrict__ b_lin,
                        float* __restrict__ out) {
    int g = blockIdx.x;
    int lane = threadIdx.x;  // 64
    float4 p = *(const float4*)(g_pooled + g * 256 + lane * 4);
    float4 w = *(const float4*)(W_lin + lane * 4);
    float s = p.x * w.x + p.y * w.y + p.z * w.z + p.w * w.w;
    for (int o = 32; o > 0; o >>= 1) s += __shfl_down(s, o);
    if (lane == 0) out[g] = s + b_lin[0];
}

// ----------------------------- host -----------------------------

extern "C" void kernel_launch(void* const* d_in, const int* in_sizes, int n_in,
                              void* d_out, int out_size, void* d_ws, size_t ws_size,
                              hipStream_t stream) {
    const float* xin   = (const float*)d_in[0];
    const float* fs    = (const float*)d_in[1];
    const int* ei      = (const int*)d_in[2];
    const int* inner   = (const int*)d_in[3];
    const int* fwd     = (const int*)d_in[4];
    const int* layers  = (const int*)d_in[6];
    const int* batch   = (const int*)d_in[7];
    const float* W_up  = (const float*)d_in[8];
    const float* b_up  = (const float*)d_in[9];
    const float* W_in  = (const float*)d_in[10];
    const float* b_in  = (const float*)d_in[11];
    const float* W_fw  = (const float*)d_in[12];
    const float* b_fw  = (const float*)d_in[13];
    const float* W_lin = (const float*)d_in[14];
    const float* b_lin = (const float*)d_in[15];
    float* out = (float*)d_out;

    // --- CSR build + weight split + fs bf16 copy ---
    k_init<<<(NSETS * N_NODES + 255) / 256, 256, 0, stream>>>();
    k_fsb<<<(N_NODES * 32 + 255) / 256, 256, 0, stream>>>(fs);
    k_wt<<<(288 * 256 + 255) / 256, 256, 0, stream>>>(W_in, 0);
    k_wt<<<(288 * 256 + 255) / 256, 256, 0, stream>>>(W_fw, 1);
    k_count_all<<<(CSR_TOTAL + 255) / 256, 256, 0, stream>>>(ei, inner, fwd);
    k_dinv<<<(NSETS * N_NODES + 255) / 256, 256, 0, stream>>>();
    k_scan<<<NSETS, SCAN_T, 0, stream>>>();
    k_fill_all<<<(CSR_TOTAL + 255) / 256, 256, 0, stream>>>(ei, inner, fwd);
    k_lists<<<(N_NODES + 255) / 256, 256, 0, stream>>>(layers);

    // --- conv0 ---
    k_gather16<<<(N_NODES * 16 + 255) / 256, 256, 0, stream>>>(xin);
    k_gemm0<<<N_NODES / 8, 256, 0, stream>>>(W_up, b_up);

    auto conv = [&](int slot, int which, const float* bias, int layer, int topi) {
        k_conv<<<(N_NODES + 15) / 16, 256, 0, stream>>>(slot, which, bias, layer, topi);
    };

    for (int p = 0; p < NPROP; p++) {
        for (int il = 0; il < NLAYERS; il++) {
            if (il < NLAYERS - 1) {
                conv(1 + il, 0, b_in, il, 0);
                conv(5 + il, 1, b_fw, il + 1, 0);   // il=3 fwd is dead
            } else {
                conv(1 + il, 0, b_in, -1, 1);       // full -> partial_inner
                k_copy_rows<<<12500, 256, 0, stream>>>(3);
            }
        }
        k_relu<<<(N_NODES * 32 + 255) / 256, 256, 0, stream>>>();
        for (int il = NLAYERS - 1; il >= 0; il--) {
            if (il >= 1) k_copy_rows<<<12500, 256, 0, stream>>>(il - 1);
            conv(1 + il, 0, b_in, il, 0);
        }
        k_relu<<<(N_NODES * 32 + 255) / 256, 256, 0, stream>>>();
    }

    k_pool<<<(N_NODES + 127) / 128, 256, 0, stream>>>(batch);
    k_final<<<NGRAPHS, 64, 0, stream>>>(W_lin, b_lin, out);
}

// Round 9
// 1741.661 us; speedup vs baseline: 1.3411x; 1.3411x over previous
//
#include <hip/hip_runtime.h>

#define N_NODES 100000
#define NLAYERS 4
#define NPROP 2
#define NGRAPHS 50
#define NE_MAIN 400000
#define NE_SET 300000
#define NSETS 9            // 0=main, 1..4=inner, 5..8=fwd
#define CSR_TOTAL (NE_MAIN + 8 * NE_SET)
#define ASTR 296           // LDS agg row stride (shorts)
#define WFSZ (9 * 16 * 512)  // fragment-ordered W: 9 kb x 16 nt x 64 lane x 8 = 73728 shorts

typedef __attribute__((ext_vector_type(8))) short bf8_t;  // 8 bf16 (4 VGPRs)
typedef __attribute__((ext_vector_type(4))) float f4_t;

// ---------------- static device scratch ----------------
// x / pi / fs-copy stored as bf16 (2 B/elem).
__device__ __align__(16) unsigned short g_x[(size_t)N_NODES * 256];
__device__ __align__(16) unsigned short g_pi[(size_t)N_NODES * 256];
__device__ __align__(16) unsigned short g_fsb[(size_t)N_NODES * 32];
__device__ __align__(16) float g_agg16[(size_t)N_NODES * 16];
__device__ __align__(16) float g_dinv[NSETS * N_NODES];
__device__ __align__(16) float g_pooled[NGRAPHS * 256];
// W in MFMA-fragment order, [which][kb][nt][lane][8]: coalesced 1 KB wave loads
__device__ __align__(16) unsigned short g_Wfh[2 * WFSZ];
__device__ __align__(16) unsigned short g_Wfl[2 * WFSZ];
__device__ int g_deg[NSETS * N_NODES];
__device__ int g_cur[NSETS * N_NODES];
__device__ int g_off[NSETS * (N_NODES + 1)];
__device__ __align__(8) int2 g_csr[CSR_TOTAL];   // {src, float_bits(nrm)}
__device__ int g_cnt[4];
__device__ int g_lists[NLAYERS * N_NODES];

__host__ __device__ inline int csr_base(int slot) {
    return slot == 0 ? 0 : NE_MAIN + (slot - 1) * NE_SET;
}

__device__ inline unsigned short f2bf(float f) {  // RNE fp32 -> bf16
    unsigned u = __float_as_uint(f);
    return (unsigned short)((u + 0x7fffu + ((u >> 16) & 1u)) >> 16);
}
__device__ inline float bf2f(unsigned short b) {
    return __uint_as_float(((unsigned)b) << 16);
}
__device__ inline float4 ldbf4(const unsigned short* p) {
    ushort4 u = *(const ushort4*)p;
    float4 f;
    f.x = bf2f(u.x); f.y = bf2f(u.y); f.z = bf2f(u.z); f.w = bf2f(u.w);
    return f;
}

// decompose linear edge id over [main | inner0..3 | fwd0..3]
__device__ inline void edge_decode(int t, const int* ei, const int* inner, const int* fwd,
                                   int& slot, const int*& es, const int*& ed, int& e) {
    if (t < NE_MAIN) {
        slot = 0; e = t; es = ei; ed = ei + NE_MAIN;
    } else {
        int r = t - NE_MAIN;
        int grp = r / NE_SET;          // 0..7
        e = r - grp * NE_SET;
        slot = 1 + grp;                // 1..4 inner, 5..8 fwd
        const int* base = (grp < 4) ? (inner + grp * 2 * NE_SET)
                                    : (fwd + (grp - 4) * 2 * NE_SET);
        es = base; ed = base + NE_SET;
    }
}

// ----------------------------- setup -----------------------------

__global__ __launch_bounds__(256) void k_init() {
    int i = blockIdx.x * blockDim.x + threadIdx.x;
    if (i < NSETS * N_NODES) g_deg[i] = 0;
    if (i < NGRAPHS * 256) g_pooled[i] = 0.f;
    if (i < 4) g_cnt[i] = 0;
}

__global__ __launch_bounds__(256) void k_fsb(const float* __restrict__ fs) {
    int i = blockIdx.x * blockDim.x + threadIdx.x;
    if (i < N_NODES * 32) g_fsb[i] = f2bf(fs[i]);
}

__global__ __launch_bounds__(256) void k_count_all(const int* __restrict__ ei,
                                                   const int* __restrict__ inner,
                                                   const int* __restrict__ fwd) {
    int t = blockIdx.x * blockDim.x + threadIdx.x;
    if (t >= CSR_TOTAL) return;
    int slot, e; const int *es, *ed;
    edge_decode(t, ei, inner, fwd, slot, es, ed, e);
    atomicAdd(&g_deg[slot * N_NODES + ed[e]], 1);
}

__global__ __launch_bounds__(256) void k_dinv() {
    int i = blockIdx.x * blockDim.x + threadIdx.x;
    if (i < NSETS * N_NODES) g_dinv[i] = rsqrtf(1.0f + (float)g_deg[i]);
}

// split W into bf16 hi/lo, stored in MFMA B-fragment order:
// element (k,n): kb=k/32, quad=(k%32)/8, ke=k%8, nt=n/16, m=n%16, lane=quad*16+m
// short index = (kb*16+nt)*512 + lane*8 + ke  -> wave B-load is contiguous 1 KB
__global__ __launch_bounds__(256) void k_wt(const float* __restrict__ W, int which) {
    int t = blockIdx.x * blockDim.x + threadIdx.x;  // over 288*256
    if (t >= 288 * 256) return;
    int k = t >> 8, n = t & 255;
    int kb = k >> 5, kq = k & 31, quad = kq >> 3, ke = kq & 7;
    int nt = n >> 4, m = n & 15, lane = quad * 16 + m;
    int idx = which * WFSZ + (kb * 16 + nt) * 512 + lane * 8 + ke;
    float w = W[t];
    unsigned short h = f2bf(w);
    unsigned short l = f2bf(w - bf2f(h));
    g_Wfh[idx] = h;
    g_Wfl[idx] = l;
}

#define SCAN_T 1024
#define SCAN_SEQ 8
__global__ __launch_bounds__(SCAN_T) void k_scan() {  // one block per set; seeds g_cur=off
    int set = blockIdx.x;
    const int* deg = g_deg + (size_t)set * N_NODES;
    int* off = g_off + (size_t)set * (N_NODES + 1);
    int* cur = g_cur + (size_t)set * N_NODES;
    __shared__ int sm[SCAN_T];
    __shared__ int s_carry;
    int t = threadIdx.x;
    if (t == 0) s_carry = 0;
    __syncthreads();
    for (int base = 0; base < N_NODES; base += SCAN_T * SCAN_SEQ) {
        int v[SCAN_SEQ];
        int sum = 0;
        int idx0 = base + t * SCAN_SEQ;
#pragma unroll
        for (int j = 0; j < SCAN_SEQ; j++) {
            int id = idx0 + j;
            v[j] = (id < N_NODES) ? deg[id] : 0;
            sum += v[j];
        }
        sm[t] = sum;
        __syncthreads();
        for (int o = 1; o < SCAN_T; o <<= 1) {
            int u = (t >= o) ? sm[t - o] : 0;
            __syncthreads();
            sm[t] += u;
            __syncthreads();
        }
        int total = sm[SCAN_T - 1];
        int run = s_carry + sm[t] - sum;
#pragma unroll
        for (int j = 0; j < SCAN_SEQ; j++) {
            int id = idx0 + j;
            if (id < N_NODES) { off[id] = run; cur[id] = run; }
            run += v[j];
        }
        __syncthreads();
        if (t == 0) s_carry += total;
        __syncthreads();
    }
    if (t == 0) off[N_NODES] = s_carry;
}

__global__ __launch_bounds__(256) void k_fill_all(const int* __restrict__ ei,
                                                  const int* __restrict__ inner,
                                                  const int* __restrict__ fwd) {
    int t = blockIdx.x * blockDim.x + threadIdx.x;
    if (t >= CSR_TOTAL) return;
    int slot, e; const int *es, *ed;
    edge_decode(t, ei, inner, fwd, slot, es, ed, e);
    int s = es[e], d = ed[e];
    int pos = atomicAdd(&g_cur[slot * N_NODES + d], 1);   // absolute slot
    float nrm = g_dinv[slot * N_NODES + s] * g_dinv[slot * N_NODES + d];
    g_csr[csr_base(slot) + pos] = make_int2(s, __float_as_int(nrm));
}

// block-local histogram -> 4 global atomics per block
__global__ __launch_bounds__(256) void k_lists(const int* __restrict__ layers) {
    __shared__ int lcnt[4];
    __shared__ int lbase[4];
    int i = blockIdx.x * blockDim.x + threadIdx.x;
    if (threadIdx.x < 4) lcnt[threadIdx.x] = 0;
    __syncthreads();
    int l = -1, p = 0;
    if (i < N_NODES) {
        l = layers[i];
        p = atomicAdd(&lcnt[l], 1);
    }
    __syncthreads();
    if (threadIdx.x < 4) lbase[threadIdx.x] = atomicAdd(&g_cnt[threadIdx.x], lcnt[threadIdx.x]);
    __syncthreads();
    if (l >= 0) g_lists[l * N_NODES + lbase[l] + p] = i;
}

// ----------------------------- conv0 (K=16) -----------------------------

__global__ __launch_bounds__(256) void k_gather16(const float* __restrict__ xin) {
    int g = blockIdx.x * blockDim.x + threadIdx.x;
    int i = g >> 4, lane = g & 15;
    if (i >= N_NODES) return;
    float dv = g_dinv[i];
    float acc = dv * dv * xin[i * 16 + lane];
    int e0 = g_off[i], e1 = g_off[i + 1];
    for (int e = e0; e < e1; e++) {
        int2 sn = g_csr[e];
        acc += __int_as_float(sn.y) * xin[sn.x * 16 + lane];
    }
    g_agg16[i * 16 + lane] = acc;
}

__global__ __launch_bounds__(256) void k_gemm0(const float* __restrict__ W,
                                               const float* __restrict__ bias) {
    __shared__ float a[128];
    int base = blockIdx.x * 8;
    int t = threadIdx.x;
    if (t < 128) a[t] = g_agg16[base * 16 + t];
    __syncthreads();
    float bb = bias[t];
    for (int r = 0; r < 8; r++) {
        float acc = bb;
#pragma unroll
        for (int k = 0; k < 16; k++) acc += a[r * 16 + k] * W[k * 256 + t];
        g_x[(size_t)(base + r) * 256 + t] = f2bf(acc);
    }
}

// -------- fused conv: bf16 CSR gather -> LDS (hi/lo) -> 3-term MFMA GEMM --------
// block: 32 rows x 256 cols, 4 waves. Phase 1: wave w gathers rows w*8..w*8+7.
// Phase 2: wave w computes col stripe w*64..+63; B-fragments are coalesced 1 KB
// wave loads from fragment-ordered g_Wf*.

__global__ __launch_bounds__(256, 4) void k_conv(int slot, int which,
                                                 const float* __restrict__ bias,
                                                 int layer, int topi) {
    int count = (layer >= 0) ? g_cnt[layer] : N_NODES;
    int base = blockIdx.x * 32;
    if (base >= count) return;
    const unsigned short* Wfh = g_Wfh + (size_t)which * WFSZ;
    const unsigned short* Wfl = g_Wfl + (size_t)which * WFSZ;
    unsigned short* out = topi ? g_pi : g_x;

    __shared__ unsigned short lds_h[32 * ASTR];
    __shared__ unsigned short lds_l[32 * ASTR];
    __shared__ int rows_s[32];
    int t = threadIdx.x;
    if (t < 32) {
        int r = base + t;
        rows_s[t] = (r < count) ? ((layer >= 0) ? g_lists[layer * N_NODES + r] : r) : -1;
    }
    __syncthreads();

    int wv = t >> 6, lane = t & 63;

    // ---- phase 1: gather 8 rows per wave into LDS ----
    const int* offp = g_off + (size_t)slot * (N_NODES + 1);
    int cb = csr_base(slot);
    for (int rr = 0; rr < 8; rr++) {
        int lr = wv * 8 + rr;
        int row = rows_s[lr];
        float4 acc = {0.f, 0.f, 0.f, 0.f};
        float4 accb = {0.f, 0.f, 0.f, 0.f};
        float4 accs = {0.f, 0.f, 0.f, 0.f};
        float4 accsb = {0.f, 0.f, 0.f, 0.f};
        if (row >= 0) {
            float dv = g_dinv[(size_t)slot * N_NODES + row];
            float d2 = dv * dv;
            acc = ldbf4(&g_x[(size_t)row * 256 + lane * 4]);
            acc.x *= d2; acc.y *= d2; acc.z *= d2; acc.w *= d2;
            if (lane < 8) {
                accs = ldbf4(&g_fsb[(size_t)row * 32 + lane * 4]);
                accs.x *= d2; accs.y *= d2; accs.z *= d2; accs.w *= d2;
            }
            int e0 = offp[row] + cb, e1 = offp[row + 1] + cb;
            int e = e0;
            for (; e + 1 < e1; e += 2) {   // 2 independent chains
                int2 sa = g_csr[e];
                int2 sb = g_csr[e + 1];
                float na = __int_as_float(sa.y);
                float nb = __int_as_float(sb.y);
                float4 va = ldbf4(&g_x[(size_t)sa.x * 256 + lane * 4]);
                float4 vb = ldbf4(&g_x[(size_t)sb.x * 256 + lane * 4]);
                acc.x += na * va.x; acc.y += na * va.y;
                acc.z += na * va.z; acc.w += na * va.w;
                accb.x += nb * vb.x; accb.y += nb * vb.y;
                accb.z += nb * vb.z; accb.w += nb * vb.w;
                if (lane < 8) {
                    float4 fa = ldbf4(&g_fsb[(size_t)sa.x * 32 + lane * 4]);
                    float4 fb = ldbf4(&g_fsb[(size_t)sb.x * 32 + lane * 4]);
                    accs.x += na * fa.x; accs.y += na * fa.y;
                    accs.z += na * fa.z; accs.w += na * fa.w;
                    accsb.x += nb * fb.x; accsb.y += nb * fb.y;
                    accsb.z += nb * fb.z; accsb.w += nb * fb.w;
                }
            }
            if (e < e1) {
                int2 sa = g_csr[e];
                float na = __int_as_float(sa.y);
                float4 va = ldbf4(&g_x[(size_t)sa.x * 256 + lane * 4]);
                acc.x += na * va.x; acc.y += na * va.y;
                acc.z += na * va.z; acc.w += na * va.w;
                if (lane < 8) {
                    float4 fa = ldbf4(&g_fsb[(size_t)sa.x * 32 + lane * 4]);
                    accs.x += na * fa.x; accs.y += na * fa.y;
                    accs.z += na * fa.z; accs.w += na * fa.w;
                }
            }
            acc.x += accb.x; acc.y += accb.y; acc.z += accb.z; acc.w += accb.w;
            accs.x += accsb.x; accs.y += accsb.y; accs.z += accsb.z; accs.w += accsb.w;
        }
        ushort4 h, l;
        h.x = f2bf(acc.x); l.x = f2bf(acc.x - bf2f(h.x));
        h.y = f2bf(acc.y); l.y = f2bf(acc.y - bf2f(h.y));
        h.z = f2bf(acc.z); l.z = f2bf(acc.z - bf2f(h.z));
        h.w = f2bf(acc.w); l.w = f2bf(acc.w - bf2f(h.w));
        *(ushort4*)&lds_h[lr * ASTR + lane * 4] = h;
        *(ushort4*)&lds_l[lr * ASTR + lane * 4] = l;
        if (lane < 8) {
            ushort4 hs, ls;
            hs.x = f2bf(accs.x); ls.x = f2bf(accs.x - bf2f(hs.x));
            hs.y = f2bf(accs.y); ls.y = f2bf(accs.y - bf2f(hs.y));
            hs.z = f2bf(accs.z); ls.z = f2bf(accs.z - bf2f(hs.z));
            hs.w = f2bf(accs.w); ls.w = f2bf(accs.w - bf2f(hs.w));
            *(ushort4*)&lds_h[lr * ASTR + 256 + lane * 4] = hs;
            *(ushort4*)&lds_l[lr * ASTR + 256 + lane * 4] = ls;
        }
    }
    __syncthreads();

    // ---- phase 2: MFMA (2 row tiles x 4 col tiles per wave) ----
    int m = lane & 15, quad = lane >> 4;
    int n0 = wv * 64;
    f4_t acc2[2][4];
#pragma unroll
    for (int rt = 0; rt < 2; rt++)
#pragma unroll
        for (int ct = 0; ct < 4; ct++) acc2[rt][ct] = (f4_t){0.f, 0.f, 0.f, 0.f};

    for (int kb = 0; kb < 9; kb++) {
        int k0 = kb * 32;
        bf8_t ah0 = *(const bf8_t*)&lds_h[m * ASTR + k0 + quad * 8];
        bf8_t al0 = *(const bf8_t*)&lds_l[m * ASTR + k0 + quad * 8];
        bf8_t ah1 = *(const bf8_t*)&lds_h[(16 + m) * ASTR + k0 + quad * 8];
        bf8_t al1 = *(const bf8_t*)&lds_l[(16 + m) * ASTR + k0 + quad * 8];
#pragma unroll
        for (int ct = 0; ct < 4; ct++) {
            int nt = wv * 4 + ct;
            const bf8_t bh = *(const bf8_t*)&Wfh[(kb * 16 + nt) * 512 + lane * 8];
            const bf8_t bl = *(const bf8_t*)&Wfl[(kb * 16 + nt) * 512 + lane * 8];
            acc2[0][ct] = __builtin_amdgcn_mfma_f32_16x16x32_bf16(ah0, bh, acc2[0][ct], 0, 0, 0);
            acc2[0][ct] = __builtin_amdgcn_mfma_f32_16x16x32_bf16(al0, bh, acc2[0][ct], 0, 0, 0);
            acc2[0][ct] = __builtin_amdgcn_mfma_f32_16x16x32_bf16(ah0, bl, acc2[0][ct], 0, 0, 0);
            acc2[1][ct] = __builtin_amdgcn_mfma_f32_16x16x32_bf16(ah1, bh, acc2[1][ct], 0, 0, 0);
            acc2[1][ct] = __builtin_amdgcn_mfma_f32_16x16x32_bf16(al1, bh, acc2[1][ct], 0, 0, 0);
            acc2[1][ct] = __builtin_amdgcn_mfma_f32_16x16x32_bf16(ah1, bl, acc2[1][ct], 0, 0, 0);
        }
    }
    // epilogue: C/D layout col=lane&15, row=quad*4+reg
#pragma unroll
    for (int rt = 0; rt < 2; rt++) {
#pragma unroll
        for (int r = 0; r < 4; r++) {
            int row = rows_s[rt * 16 + quad * 4 + r];
            if (row < 0) continue;
#pragma unroll
            for (int ct = 0; ct < 4; ct++) {
                int n = n0 + ct * 16 + m;
                out[(size_t)row * 256 + n] = f2bf(acc2[rt][ct][r] + bias[n]);
            }
        }
    }
}

// ----------------------------- misc -----------------------------

// half-wave (32 lanes) per row, uint4 = 16 B per lane
__global__ __launch_bounds__(256) void k_copy_rows(int layer) {
    int w = (blockIdx.x * blockDim.x + threadIdx.x) >> 5;
    int lane = threadIdx.x & 31;
    if (w >= g_cnt[layer]) return;
    int i = g_lists[layer * N_NODES + w];
    *(uint4*)(g_x + (size_t)i * 256 + lane * 8) =
        *(const uint4*)(g_pi + (size_t)i * 256 + lane * 8);
}

__global__ __launch_bounds__(256) void k_relu() {
    int i = blockIdx.x * blockDim.x + threadIdx.x;  // over N*256/8
    if (i >= N_NODES * 32) return;
    ushort4 a = ((ushort4*)g_x)[i * 2];
    ushort4 b = ((ushort4*)g_x)[i * 2 + 1];
    a.x = (a.x & 0x8000) ? 0 : a.x; a.y = (a.y & 0x8000) ? 0 : a.y;
    a.z = (a.z & 0x8000) ? 0 : a.z; a.w = (a.w & 0x8000) ? 0 : a.w;
    b.x = (b.x & 0x8000) ? 0 : b.x; b.y = (b.y & 0x8000) ? 0 : b.y;
    b.z = (b.z & 0x8000) ? 0 : b.z; b.w = (b.w & 0x8000) ? 0 : b.w;
    ((ushort4*)g_x)[i * 2] = a;
    ((ushort4*)g_x)[i * 2 + 1] = b;
}

__global__ __launch_bounds__(256) void k_pool(const int* __restrict__ batch) {
    __shared__ int bs[128];
    int i0 = blockIdx.x * 128;
    if (threadIdx.x < 128) {
        int i = i0 + threadIdx.x;
        bs[threadIdx.x] = (i < N_NODES) ? batch[i] : -1;
    }
    __syncthreads();
    int c = threadIdx.x;
    int lim = min(128, N_NODES - i0);
    float acc = 0.f;
    int cur = bs[0];
    for (int ii = 0; ii < lim; ii++) {
        int g = bs[ii];
        if (g != cur) { atomicAdd(&g_pooled[cur * 256 + c], acc); acc = 0.f; cur = g; }
        acc += bf2f(g_x[(size_t)(i0 + ii) * 256 + c]);
    }
    atomicAdd(&g_pooled[cur * 256 + c], acc);
}

__global__ void k_final(const float* __restrict__ W_lin, const float* __restrict__ b_lin,
                        float* __restrict__ out) {
    int g = blockIdx.x;
    int lane = threadIdx.x;  // 64
    float4 p = *(const float4*)(g_pooled + g * 256 + lane * 4);
    float4 w = *(const float4*)(W_lin + lane * 4);
    float s = p.x * w.x + p.y * w.y + p.z * w.z + p.w * w.w;
    for (int o = 32; o > 0; o >>= 1) s += __shfl_down(s, o);
    if (lane == 0) out[g] = s + b_lin[0];
}

// ----------------------------- host -----------------------------

extern "C" void kernel_launch(void* const* d_in, const int* in_sizes, int n_in,
                              void* d_out, int out_size, void* d_ws, size_t ws_size,
                              hipStream_t stream) {
    const float* xin   = (const float*)d_in[0];
    const float* fs    = (const float*)d_in[1];
    const int* ei      = (const int*)d_in[2];
    const int* inner   = (const int*)d_in[3];
    const int* fwd     = (const int*)d_in[4];
    const int* layers  = (const int*)d_in[6];
    const int* batch   = (const int*)d_in[7];
    const float* W_up  = (const float*)d_in[8];
    const float* b_up  = (const float*)d_in[9];
    const float* W_in  = (const float*)d_in[10];
    const float* b_in  = (const float*)d_in[11];
    const float* W_fw  = (const float*)d_in[12];
    const float* b_fw  = (const float*)d_in[13];
    const float* W_lin = (const float*)d_in[14];
    const float* b_lin = (const float*)d_in[15];
    float* out = (float*)d_out;

    // --- CSR build + weight split + fs bf16 copy ---
    k_init<<<(NSETS * N_NODES + 255) / 256, 256, 0, stream>>>();
    k_fsb<<<(N_NODES * 32 + 255) / 256, 256, 0, stream>>>(fs);
    k_wt<<<(288 * 256 + 255) / 256, 256, 0, stream>>>(W_in, 0);
    k_wt<<<(288 * 256 + 255) / 256, 256, 0, stream>>>(W_fw, 1);
    k_count_all<<<(CSR_TOTAL + 255) / 256, 256, 0, stream>>>(ei, inner, fwd);
    k_dinv<<<(NSETS * N_NODES + 255) / 256, 256, 0, stream>>>();
    k_scan<<<NSETS, SCAN_T, 0, stream>>>();
    k_fill_all<<<(CSR_TOTAL + 255) / 256, 256, 0, stream>>>(ei, inner, fwd);
    k_lists<<<(N_NODES + 255) / 256, 256, 0, stream>>>(layers);

    // --- conv0 ---
    k_gather16<<<(N_NODES * 16 + 255) / 256, 256, 0, stream>>>(xin);
    k_gemm0<<<N_NODES / 8, 256, 0, stream>>>(W_up, b_up);

    auto conv = [&](int slot, int which, const float* bias, int layer, int topi) {
        k_conv<<<(N_NODES + 31) / 32, 256, 0, stream>>>(slot, which, bias, layer, topi);
    };

    for (int p = 0; p < NPROP; p++) {
        for (int il = 0; il < NLAYERS; il++) {
            if (il < NLAYERS - 1) {
                conv(1 + il, 0, b_in, il, 0);
                conv(5 + il, 1, b_fw, il + 1, 0);   // il=3 fwd is dead
            } else {
                conv(1 + il, 0, b_in, -1, 1);       // full -> partial_inner
                k_copy_rows<<<12500, 256, 0, stream>>>(3);
            }
        }
        k_relu<<<(N_NODES * 32 + 255) / 256, 256, 0, stream>>>();
        for (int il = NLAYERS - 1; il >= 0; il--) {
            if (il >= 1) k_copy_rows<<<12500, 256, 0, stream>>>(il - 1);
            conv(1 + il, 0, b_in, il, 0);
        }
        k_relu<<<(N_NODES * 32 + 255) / 256, 256, 0, stream>>>();
    }

    k_pool<<<(N_NODES + 127) / 128, 256, 0, stream>>>(batch);
    k_final<<<NGRAPHS, 64, 0, stream>>>(W_lin, b_lin, out);
}

// Round 10
// 1605.919 us; speedup vs baseline: 1.4545x; 1.0845x over previous
//
#include <hip/hip_runtime.h>

#define N_NODES 100000
#define NLAYERS 4
#define NPROP 2
#define NGRAPHS 50
#define NE_MAIN 400000
#define NE_SET 300000
#define NSETS 9            // 0=main, 1..4=inner, 5..8=fwd
#define CSR_TOTAL (NE_MAIN + 8 * NE_SET)
#define ASTR 296           // LDS agg row stride (shorts)
#define WFSZ (9 * 16 * 512)  // fragment-ordered W: 9 kb x 16 nt x 64 lane x 8 = 73728 shorts
#define PCHUNK 4096        // scan chunk (elements)
#define NCHK 25            // ceil(N_NODES / PCHUNK)

typedef __attribute__((ext_vector_type(8))) short bf8_t;  // 8 bf16 (4 VGPRs)
typedef __attribute__((ext_vector_type(4))) float f4_t;

// ---------------- static device scratch ----------------
__device__ __align__(16) unsigned short g_x[(size_t)N_NODES * 256];
__device__ __align__(16) unsigned short g_pi[(size_t)N_NODES * 256];
__device__ __align__(16) unsigned short g_fsb[(size_t)N_NODES * 32];
__device__ __align__(16) float g_agg16[(size_t)N_NODES * 16];
__device__ __align__(16) float g_dinv[NSETS * N_NODES];
__device__ __align__(16) float g_pooled[NGRAPHS * 256];
// W in MFMA-fragment order, [which][kb][nt][lane][8]: coalesced 1 KB wave loads
__device__ __align__(16) unsigned short g_Wfh[2 * WFSZ];
__device__ __align__(16) unsigned short g_Wfl[2 * WFSZ];
__device__ int g_deg[NSETS * N_NODES];
__device__ int g_cur[NSETS * N_NODES];
__device__ int g_off[NSETS * (N_NODES + 1)];
__device__ int g_part[NSETS * NCHK];
__device__ __align__(8) int2 g_csr[CSR_TOTAL];   // {src, float_bits(nrm)}
__device__ int g_cnt[4];
__device__ int g_lists[NLAYERS * N_NODES];

__host__ __device__ inline int csr_base(int slot) {
    return slot == 0 ? 0 : NE_MAIN + (slot - 1) * NE_SET;
}

__device__ inline unsigned short f2bf(float f) {  // RNE fp32 -> bf16
    unsigned u = __float_as_uint(f);
    return (unsigned short)((u + 0x7fffu + ((u >> 16) & 1u)) >> 16);
}
__device__ inline float bf2f(unsigned short b) {
    return __uint_as_float(((unsigned)b) << 16);
}
__device__ inline float4 ldbf4(const unsigned short* p) {
    ushort4 u = *(const ushort4*)p;
    float4 f;
    f.x = bf2f(u.x); f.y = bf2f(u.y); f.z = bf2f(u.z); f.w = bf2f(u.w);
    return f;
}

// decompose linear edge id over [main | inner0..3 | fwd0..3]
__device__ inline void edge_decode(int t, const int* ei, const int* inner, const int* fwd,
                                   int& slot, const int*& es, const int*& ed, int& e) {
    if (t < NE_MAIN) {
        slot = 0; e = t; es = ei; ed = ei + NE_MAIN;
    } else {
        int r = t - NE_MAIN;
        int grp = r / NE_SET;          // 0..7
        e = r - grp * NE_SET;
        slot = 1 + grp;                // 1..4 inner, 5..8 fwd
        const int* base = (grp < 4) ? (inner + grp * 2 * NE_SET)
                                    : (fwd + (grp - 4) * 2 * NE_SET);
        es = base; ed = base + NE_SET;
    }
}

// ----------------------------- setup -----------------------------

__global__ __launch_bounds__(256) void k_init() {
    int i = blockIdx.x * blockDim.x + threadIdx.x;
    if (i < NSETS * N_NODES) g_deg[i] = 0;
    if (i < NGRAPHS * 256) g_pooled[i] = 0.f;
    if (i < 4) g_cnt[i] = 0;
}

__global__ __launch_bounds__(256) void k_fsb(const float* __restrict__ fs) {
    int i = blockIdx.x * blockDim.x + threadIdx.x;
    if (i < N_NODES * 32) g_fsb[i] = f2bf(fs[i]);
}

__global__ __launch_bounds__(256) void k_count_all(const int* __restrict__ ei,
                                                   const int* __restrict__ inner,
                                                   const int* __restrict__ fwd) {
    int t = blockIdx.x * blockDim.x + threadIdx.x;
    if (t >= CSR_TOTAL) return;
    int slot, e; const int *es, *ed;
    edge_decode(t, ei, inner, fwd, slot, es, ed, e);
    atomicAdd(&g_deg[slot * N_NODES + ed[e]], 1);
}

__global__ __launch_bounds__(256) void k_dinv() {
    int i = blockIdx.x * blockDim.x + threadIdx.x;
    if (i < NSETS * N_NODES) g_dinv[i] = rsqrtf(1.0f + (float)g_deg[i]);
}

// split W into bf16 hi/lo, stored in MFMA B-fragment order
__global__ __launch_bounds__(256) void k_wt(const float* __restrict__ W, int which) {
    int t = blockIdx.x * blockDim.x + threadIdx.x;  // over 288*256
    if (t >= 288 * 256) return;
    int k = t >> 8, n = t & 255;
    int kb = k >> 5, kq = k & 31, quad = kq >> 3, ke = kq & 7;
    int nt = n >> 4, m = n & 15, lane = quad * 16 + m;
    int idx = which * WFSZ + (kb * 16 + nt) * 512 + lane * 8 + ke;
    float w = W[t];
    unsigned short h = f2bf(w);
    unsigned short l = f2bf(w - bf2f(h));
    g_Wfh[idx] = h;
    g_Wfl[idx] = l;
}

// ---- hierarchical scan: A) chunk sums  B) scan partials  C) local scan+offset ----

__global__ __launch_bounds__(256) void k_scan_a() {   // 9*25 blocks
    int b = blockIdx.x;
    int set = b / NCHK, ch = b % NCHK;
    const int* deg = g_deg + (size_t)set * N_NODES;
    int base = ch * PCHUNK + threadIdx.x * 16;
    int s = 0;
#pragma unroll
    for (int j = 0; j < 16; j++) {
        int id = base + j;
        if (id < N_NODES) s += deg[id];
    }
    __shared__ int sm[256];
    sm[threadIdx.x] = s;
    __syncthreads();
    for (int o = 128; o > 0; o >>= 1) {
        if (threadIdx.x < o) sm[threadIdx.x] += sm[threadIdx.x + o];
        __syncthreads();
    }
    if (threadIdx.x == 0) g_part[b] = sm[0];
}

__global__ __launch_bounds__(1024) void k_scan_b() {  // 1 block; wave per set
    int wv = threadIdx.x >> 6, lane = threadIdx.x & 63;
    if (wv >= NSETS) return;
    int v = (lane < NCHK) ? g_part[wv * NCHK + lane] : 0;
    int orig = v;
    for (int o = 1; o < 32; o <<= 1) {
        int u = __shfl_up(v, o);
        if (lane >= o) v += u;
    }
    if (lane < NCHK) g_part[wv * NCHK + lane] = v - orig;  // exclusive
}

__global__ __launch_bounds__(256) void k_scan_c() {   // 9*25 blocks; writes off+cur
    int b = blockIdx.x;
    int set = b / NCHK, ch = b % NCHK;
    const int* deg = g_deg + (size_t)set * N_NODES;
    int* off = g_off + (size_t)set * (N_NODES + 1);
    int* cur = g_cur + (size_t)set * N_NODES;
    int t = threadIdx.x;
    int base = ch * PCHUNK + t * 16;
    int v[16];
    int s = 0;
#pragma unroll
    for (int j = 0; j < 16; j++) {
        int id = base + j;
        v[j] = (id < N_NODES) ? deg[id] : 0;
        s += v[j];
    }
    __shared__ int sm[256];
    sm[t] = s;
    __syncthreads();
    for (int o = 1; o < 256; o <<= 1) {
        int u = (t >= o) ? sm[t - o] : 0;
        __syncthreads();
        sm[t] += u;
        __syncthreads();
    }
    int run = g_part[b] + sm[t] - s;   // exclusive prefix for this thread
#pragma unroll
    for (int j = 0; j < 16; j++) {
        int id = base + j;
        if (id < N_NODES) { off[id] = run; cur[id] = run; }
        run += v[j];
    }
    if (ch == NCHK - 1 && t == 255) off[N_NODES] = (set == 0) ? NE_MAIN : NE_SET;
}

__global__ __launch_bounds__(256) void k_fill_all(const int* __restrict__ ei,
                                                  const int* __restrict__ inner,
                                                  const int* __restrict__ fwd) {
    int t = blockIdx.x * blockDim.x + threadIdx.x;
    if (t >= CSR_TOTAL) return;
    int slot, e; const int *es, *ed;
    edge_decode(t, ei, inner, fwd, slot, es, ed, e);
    int s = es[e], d = ed[e];
    int pos = atomicAdd(&g_cur[slot * N_NODES + d], 1);   // absolute slot
    float nrm = g_dinv[slot * N_NODES + s] * g_dinv[slot * N_NODES + d];
    g_csr[csr_base(slot) + pos] = make_int2(s, __float_as_int(nrm));
}

// block-local histogram -> 4 global atomics per block
__global__ __launch_bounds__(256) void k_lists(const int* __restrict__ layers) {
    __shared__ int lcnt[4];
    __shared__ int lbase[4];
    int i = blockIdx.x * blockDim.x + threadIdx.x;
    if (threadIdx.x < 4) lcnt[threadIdx.x] = 0;
    __syncthreads();
    int l = -1, p = 0;
    if (i < N_NODES) {
        l = layers[i];
        p = atomicAdd(&lcnt[l], 1);
    }
    __syncthreads();
    if (threadIdx.x < 4) lbase[threadIdx.x] = atomicAdd(&g_cnt[threadIdx.x], lcnt[threadIdx.x]);
    __syncthreads();
    if (l >= 0) g_lists[l * N_NODES + lbase[l] + p] = i;
}

// ----------------------------- conv0 (K=16) -----------------------------

__global__ __launch_bounds__(256) void k_gather16(const float* __restrict__ xin) {
    int g = blockIdx.x * blockDim.x + threadIdx.x;
    int i = g >> 4, lane = g & 15;
    if (i >= N_NODES) return;
    float dv = g_dinv[i];
    float acc = dv * dv * xin[i * 16 + lane];
    int e0 = g_off[i], e1 = g_off[i + 1];
    for (int e = e0; e < e1; e++) {
        int2 sn = g_csr[e];
        acc += __int_as_float(sn.y) * xin[sn.x * 16 + lane];
    }
    g_agg16[i * 16 + lane] = acc;
}

__global__ __launch_bounds__(256) void k_gemm0(const float* __restrict__ W,
                                               const float* __restrict__ bias) {
    __shared__ float a[128];
    int base = blockIdx.x * 8;
    int t = threadIdx.x;
    if (t < 128) a[t] = g_agg16[base * 16 + t];
    __syncthreads();
    float bb = bias[t];
    for (int r = 0; r < 8; r++) {
        float acc = bb;
#pragma unroll
        for (int k = 0; k < 16; k++) acc += a[r * 16 + k] * W[k * 256 + t];
        g_x[(size_t)(base + r) * 256 + t] = f2bf(acc);
    }
}

// -------- fused conv: bf16 CSR gather -> LDS (hi/lo) -> 3-term MFMA GEMM --------

__global__ __launch_bounds__(256, 4) void k_conv(int slot, int which,
                                                 const float* __restrict__ bias,
                                                 int layer, int topi) {
    int count = (layer >= 0) ? g_cnt[layer] : N_NODES;
    int base = blockIdx.x * 32;
    if (base >= count) return;
    const unsigned short* Wfh = g_Wfh + (size_t)which * WFSZ;
    const unsigned short* Wfl = g_Wfl + (size_t)which * WFSZ;
    unsigned short* out = topi ? g_pi : g_x;

    __shared__ unsigned short lds_h[32 * ASTR];
    __shared__ unsigned short lds_l[32 * ASTR];
    __shared__ int rows_s[32];
    int t = threadIdx.x;
    if (t < 32) {
        int r = base + t;
        rows_s[t] = (r < count) ? ((layer >= 0) ? g_lists[layer * N_NODES + r] : r) : -1;
    }
    __syncthreads();

    int wv = t >> 6, lane = t & 63;

    // ---- phase 1: gather 8 rows per wave into LDS ----
    const int* offp = g_off + (size_t)slot * (N_NODES + 1);
    int cb = csr_base(slot);
    for (int rr = 0; rr < 8; rr++) {
        int lr = wv * 8 + rr;
        int row = rows_s[lr];
        float4 acc = {0.f, 0.f, 0.f, 0.f};
        float4 accb = {0.f, 0.f, 0.f, 0.f};
        float4 accs = {0.f, 0.f, 0.f, 0.f};
        float4 accsb = {0.f, 0.f, 0.f, 0.f};
        if (row >= 0) {
            float dv = g_dinv[(size_t)slot * N_NODES + row];
            float d2 = dv * dv;
            acc = ldbf4(&g_x[(size_t)row * 256 + lane * 4]);
            acc.x *= d2; acc.y *= d2; acc.z *= d2; acc.w *= d2;
            if (lane < 8) {
                accs = ldbf4(&g_fsb[(size_t)row * 32 + lane * 4]);
                accs.x *= d2; accs.y *= d2; accs.z *= d2; accs.w *= d2;
            }
            int e0 = offp[row] + cb, e1 = offp[row + 1] + cb;
            int e = e0;
            for (; e + 1 < e1; e += 2) {   // 2 independent chains
                int2 sa = g_csr[e];
                int2 sb = g_csr[e + 1];
                float na = __int_as_float(sa.y);
                float nb = __int_as_float(sb.y);
                float4 va = ldbf4(&g_x[(size_t)sa.x * 256 + lane * 4]);
                float4 vb = ldbf4(&g_x[(size_t)sb.x * 256 + lane * 4]);
                acc.x += na * va.x; acc.y += na * va.y;
                acc.z += na * va.z; acc.w += na * va.w;
                accb.x += nb * vb.x; accb.y += nb * vb.y;
                accb.z += nb * vb.z; accb.w += nb * vb.w;
                if (lane < 8) {
                    float4 fa = ldbf4(&g_fsb[(size_t)sa.x * 32 + lane * 4]);
                    float4 fb = ldbf4(&g_fsb[(size_t)sb.x * 32 + lane * 4]);
                    accs.x += na * fa.x; accs.y += na * fa.y;
                    accs.z += na * fa.z; accs.w += na * fa.w;
                    accsb.x += nb * fb.x; accsb.y += nb * fb.y;
                    accsb.z += nb * fb.z; accsb.w += nb * fb.w;
                }
            }
            if (e < e1) {
                int2 sa = g_csr[e];
                float na = __int_as_float(sa.y);
                float4 va = ldbf4(&g_x[(size_t)sa.x * 256 + lane * 4]);
                acc.x += na * va.x; acc.y += na * va.y;
                acc.z += na * va.z; acc.w += na * va.w;
                if (lane < 8) {
                    float4 fa = ldbf4(&g_fsb[(size_t)sa.x * 32 + lane * 4]);
                    accs.x += na * fa.x; accs.y += na * fa.y;
                    accs.z += na * fa.z; accs.w += na * fa.w;
                }
            }
            acc.x += accb.x; acc.y += accb.y; acc.z += accb.z; acc.w += accb.w;
            accs.x += accsb.x; accs.y += accsb.y; accs.z += accsb.z; accs.w += accsb.w;
        }
        ushort4 h, l;
        h.x = f2bf(acc.x); l.x = f2bf(acc.x - bf2f(h.x));
        h.y = f2bf(acc.y); l.y = f2bf(acc.y - bf2f(h.y));
        h.z = f2bf(acc.z); l.z = f2bf(acc.z - bf2f(h.z));
        h.w = f2bf(acc.w); l.w = f2bf(acc.w - bf2f(h.w));
        *(ushort4*)&lds_h[lr * ASTR + lane * 4] = h;
        *(ushort4*)&lds_l[lr * ASTR + lane * 4] = l;
        if (lane < 8) {
            ushort4 hs, ls;
            hs.x = f2bf(accs.x); ls.x = f2bf(accs.x - bf2f(hs.x));
            hs.y = f2bf(accs.y); ls.y = f2bf(accs.y - bf2f(hs.y));
            hs.z = f2bf(accs.z); ls.z = f2bf(accs.z - bf2f(hs.z));
            hs.w = f2bf(accs.w); ls.w = f2bf(accs.w - bf2f(hs.w));
            *(ushort4*)&lds_h[lr * ASTR + 256 + lane * 4] = hs;
            *(ushort4*)&lds_l[lr * ASTR + 256 + lane * 4] = ls;
        }
    }
    __syncthreads();

    // ---- phase 2: MFMA (2 row tiles x 4 col tiles per wave) ----
    int m = lane & 15, quad = lane >> 4;
    int n0 = wv * 64;
    f4_t acc2[2][4];
#pragma unroll
    for (int rt = 0; rt < 2; rt++)
#pragma unroll
        for (int ct = 0; ct < 4; ct++) acc2[rt][ct] = (f4_t){0.f, 0.f, 0.f, 0.f};

    for (int kb = 0; kb < 9; kb++) {
        int k0 = kb * 32;
        bf8_t ah0 = *(const bf8_t*)&lds_h[m * ASTR + k0 + quad * 8];
        bf8_t al0 = *(const bf8_t*)&lds_l[m * ASTR + k0 + quad * 8];
        bf8_t ah1 = *(const bf8_t*)&lds_h[(16 + m) * ASTR + k0 + quad * 8];
        bf8_t al1 = *(const bf8_t*)&lds_l[(16 + m) * ASTR + k0 + quad * 8];
#pragma unroll
        for (int ct = 0; ct < 4; ct++) {
            int nt = wv * 4 + ct;
            const bf8_t bh = *(const bf8_t*)&Wfh[(kb * 16 + nt) * 512 + lane * 8];
            const bf8_t bl = *(const bf8_t*)&Wfl[(kb * 16 + nt) * 512 + lane * 8];
            acc2[0][ct] = __builtin_amdgcn_mfma_f32_16x16x32_bf16(ah0, bh, acc2[0][ct], 0, 0, 0);
            acc2[0][ct] = __builtin_amdgcn_mfma_f32_16x16x32_bf16(al0, bh, acc2[0][ct], 0, 0, 0);
            acc2[0][ct] = __builtin_amdgcn_mfma_f32_16x16x32_bf16(ah0, bl, acc2[0][ct], 0, 0, 0);
            acc2[1][ct] = __builtin_amdgcn_mfma_f32_16x16x32_bf16(ah1, bh, acc2[1][ct], 0, 0, 0);
            acc2[1][ct] = __builtin_amdgcn_mfma_f32_16x16x32_bf16(al1, bh, acc2[1][ct], 0, 0, 0);
            acc2[1][ct] = __builtin_amdgcn_mfma_f32_16x16x32_bf16(ah1, bl, acc2[1][ct], 0, 0, 0);
        }
    }
    // epilogue: C/D layout col=lane&15, row=quad*4+reg
#pragma unroll
    for (int rt = 0; rt < 2; rt++) {
#pragma unroll
        for (int r = 0; r < 4; r++) {
            int row = rows_s[rt * 16 + quad * 4 + r];
            if (row < 0) continue;
#pragma unroll
            for (int ct = 0; ct < 4; ct++) {
                int n = n0 + ct * 16 + m;
                out[(size_t)row * 256 + n] = f2bf(acc2[rt][ct][r] + bias[n]);
            }
        }
    }
}

// ----------------------------- misc -----------------------------

__global__ __launch_bounds__(256) void k_copy_rows(int layer) {
    int w = (blockIdx.x * blockDim.x + threadIdx.x) >> 5;
    int lane = threadIdx.x & 31;
    if (w >= g_cnt[layer]) return;
    int i = g_lists[layer * N_NODES + w];
    *(uint4*)(g_x + (size_t)i * 256 + lane * 8) =
        *(const uint4*)(g_pi + (size_t)i * 256 + lane * 8);
}

__global__ __launch_bounds__(256) void k_relu() {
    int i = blockIdx.x * blockDim.x + threadIdx.x;  // over N*256/8
    if (i >= N_NODES * 32) return;
    ushort4 a = ((ushort4*)g_x)[i * 2];
    ushort4 b = ((ushort4*)g_x)[i * 2 + 1];
    a.x = (a.x & 0x8000) ? 0 : a.x; a.y = (a.y & 0x8000) ? 0 : a.y;
    a.z = (a.z & 0x8000) ? 0 : a.z; a.w = (a.w & 0x8000) ? 0 : a.w;
    b.x = (b.x & 0x8000) ? 0 : b.x; b.y = (b.y & 0x8000) ? 0 : b.y;
    b.z = (b.z & 0x8000) ? 0 : b.z; b.w = (b.w & 0x8000) ? 0 : b.w;
    ((ushort4*)g_x)[i * 2] = a;
    ((ushort4*)g_x)[i * 2 + 1] = b;
}

// pool with fused final ReLU (x is dead after pooling)
__global__ __launch_bounds__(256) void k_pool(const int* __restrict__ batch) {
    __shared__ int bs[128];
    int i0 = blockIdx.x * 128;
    if (threadIdx.x < 128) {
        int i = i0 + threadIdx.x;
        bs[threadIdx.x] = (i < N_NODES) ? batch[i] : -1;
    }
    __syncthreads();
    int c = threadIdx.x;
    int lim = min(128, N_NODES - i0);
    float acc = 0.f;
    int cur = bs[0];
    for (int ii = 0; ii < lim; ii++) {
        int g = bs[ii];
        if (g != cur) { atomicAdd(&g_pooled[cur * 256 + c], acc); acc = 0.f; cur = g; }
        acc += fmaxf(bf2f(g_x[(size_t)(i0 + ii) * 256 + c]), 0.f);
    }
    atomicAdd(&g_pooled[cur * 256 + c], acc);
}

__global__ void k_final(const float* __restrict__ W_lin, const float* __restrict__ b_lin,
                        float* __restrict__ out) {
    int g = blockIdx.x;
    int lane = threadIdx.x;  // 64
    float4 p = *(const float4*)(g_pooled + g * 256 + lane * 4);
    float4 w = *(const float4*)(W_lin + lane * 4);
    float s = p.x * w.x + p.y * w.y + p.z * w.z + p.w * w.w;
    for (int o = 32; o > 0; o >>= 1) s += __shfl_down(s, o);
    if (lane == 0) out[g] = s + b_lin[0];
}

// ----------------------------- host -----------------------------

extern "C" void kernel_launch(void* const* d_in, const int* in_sizes, int n_in,
                              void* d_out, int out_size, void* d_ws, size_t ws_size,
                              hipStream_t stream) {
    const float* xin   = (const float*)d_in[0];
    const float* fs    = (const float*)d_in[1];
    const int* ei      = (const int*)d_in[2];
    const int* inner   = (const int*)d_in[3];
    const int* fwd     = (const int*)d_in[4];
    const int* layers  = (const int*)d_in[6];
    const int* batch   = (const int*)d_in[7];
    const float* W_up  = (const float*)d_in[8];
    const float* b_up  = (const float*)d_in[9];
    const float* W_in  = (const float*)d_in[10];
    const float* b_in  = (const float*)d_in[11];
    const float* W_fw  = (const float*)d_in[12];
    const float* b_fw  = (const float*)d_in[13];
    const float* W_lin = (const float*)d_in[14];
    const float* b_lin = (const float*)d_in[15];
    float* out = (float*)d_out;

    // --- CSR build + weight split + fs bf16 copy ---
    k_init<<<(NSETS * N_NODES + 255) / 256, 256, 0, stream>>>();
    k_fsb<<<(N_NODES * 32 + 255) / 256, 256, 0, stream>>>(fs);
    k_wt<<<(288 * 256 + 255) / 256, 256, 0, stream>>>(W_in, 0);
    k_wt<<<(288 * 256 + 255) / 256, 256, 0, stream>>>(W_fw, 1);
    k_count_all<<<(CSR_TOTAL + 255) / 256, 256, 0, stream>>>(ei, inner, fwd);
    k_dinv<<<(NSETS * N_NODES + 255) / 256, 256, 0, stream>>>();
    k_scan_a<<<NSETS * NCHK, 256, 0, stream>>>();
    k_scan_b<<<1, 1024, 0, stream>>>();
    k_scan_c<<<NSETS * NCHK, 256, 0, stream>>>();
    k_fill_all<<<(CSR_TOTAL + 255) / 256, 256, 0, stream>>>(ei, inner, fwd);
    k_lists<<<(N_NODES + 255) / 256, 256, 0, stream>>>(layers);

    // --- conv0 ---
    k_gather16<<<(N_NODES * 16 + 255) / 256, 256, 0, stream>>>(xin);
    k_gemm0<<<N_NODES / 8, 256, 0, stream>>>(W_up, b_up);

    auto conv = [&](int slot, int which, const float* bias, int layer, int topi) {
        k_conv<<<(N_NODES + 31) / 32, 256, 0, stream>>>(slot, which, bias, layer, topi);
    };

    for (int p = 0; p < NPROP; p++) {
        for (int il = 0; il < NLAYERS; il++) {
            if (il < NLAYERS - 1) {
                conv(1 + il, 0, b_in, il, 0);
                conv(5 + il, 1, b_fw, il + 1, 0);   // il=3 fwd is dead
            } else {
                conv(1 + il, 0, b_in, -1, 1);       // full -> partial_inner
                k_copy_rows<<<12500, 256, 0, stream>>>(3);
            }
        }
        k_relu<<<(N_NODES * 32 + 255) / 256, 256, 0, stream>>>();
        for (int il = NLAYERS - 1; il >= 0; il--) {
            if (il >= 1) k_copy_rows<<<12500, 256, 0, stream>>>(il - 1);
            conv(1 + il, 0, b_in, il, 0);
        }
        if (p < NPROP - 1)   // final relu fused into k_pool
            k_relu<<<(N_NODES * 32 + 255) / 256, 256, 0, stream>>>();
    }

    k_pool<<<(N_NODES + 127) / 128, 256, 0, stream>>>(batch);
    k_final<<<NGRAPHS, 64, 0, stream>>>(W_lin, b_lin, out);
}

// Round 11
// 1507.914 us; speedup vs baseline: 1.5490x; 1.0650x over previous
//
#include <hip/hip_runtime.h>

#define N_NODES 100000
#define NLAYERS 4
#define NPROP 2
#define NGRAPHS 50
#define NE_MAIN 400000
#define NE_SET 300000
#define NSETS 9            // 0=main, 1..4=inner, 5..8=fwd
#define CSR_TOTAL (NE_MAIN + 8 * NE_SET)
#define ASTR 296           // LDS agg row stride (shorts)
#define WFSZ (9 * 16 * 512)  // fragment-ordered W
#define PCHUNK 4096
#define NCHK 25

typedef __attribute__((ext_vector_type(8))) short bf8_t;
typedef __attribute__((ext_vector_type(8))) unsigned short us8_t;
typedef __attribute__((ext_vector_type(4))) float f4_t;

// ---------------- static device scratch ----------------
__device__ __align__(16) unsigned short g_x[(size_t)N_NODES * 256];
__device__ __align__(16) unsigned short g_pi[(size_t)N_NODES * 256];
__device__ __align__(16) unsigned short g_fsb[(size_t)N_NODES * 32];
__device__ __align__(16) float g_agg16[(size_t)N_NODES * 16];
__device__ __align__(16) float g_dinv[NSETS * N_NODES];
__device__ __align__(16) float g_pooled[NGRAPHS * 256];
__device__ __align__(16) unsigned short g_Wfh[2 * WFSZ];
__device__ __align__(16) unsigned short g_Wfl[2 * WFSZ];
__device__ int g_deg[NSETS * N_NODES];
__device__ int g_cur[NSETS * N_NODES];
__device__ int g_off[NSETS * (N_NODES + 1)];
__device__ int g_part[NSETS * NCHK];
__device__ int g_csrs[CSR_TOTAL];   // src only; nrm recomputed from dinv
__device__ int g_cnt[4];
__device__ int g_lists[NLAYERS * N_NODES];

__host__ __device__ inline int csr_base(int slot) {
    return slot == 0 ? 0 : NE_MAIN + (slot - 1) * NE_SET;
}

__device__ inline unsigned short f2bf(float f) {
    unsigned u = __float_as_uint(f);
    return (unsigned short)((u + 0x7fffu + ((u >> 16) & 1u)) >> 16);
}
__device__ inline float bf2f(unsigned short b) {
    return __uint_as_float(((unsigned)b) << 16);
}

__device__ inline void edge_decode(int t, const int* ei, const int* inner, const int* fwd,
                                   int& slot, const int*& es, const int*& ed, int& e) {
    if (t < NE_MAIN) {
        slot = 0; e = t; es = ei; ed = ei + NE_MAIN;
    } else {
        int r = t - NE_MAIN;
        int grp = r / NE_SET;
        e = r - grp * NE_SET;
        slot = 1 + grp;
        const int* base = (grp < 4) ? (inner + grp * 2 * NE_SET)
                                    : (fwd + (grp - 4) * 2 * NE_SET);
        es = base; ed = base + NE_SET;
    }
}

// ----------------------------- setup -----------------------------

__global__ __launch_bounds__(256) void k_init() {
    int i = blockIdx.x * blockDim.x + threadIdx.x;
    if (i < NSETS * N_NODES) g_deg[i] = 0;
    if (i < NGRAPHS * 256) g_pooled[i] = 0.f;
    if (i < 4) g_cnt[i] = 0;
}

__global__ __launch_bounds__(256) void k_fsb(const float* __restrict__ fs) {
    int i = blockIdx.x * blockDim.x + threadIdx.x;
    if (i < N_NODES * 32) g_fsb[i] = f2bf(fs[i]);
}

__global__ __launch_bounds__(256) void k_count_all(const int* __restrict__ ei,
                                                   const int* __restrict__ inner,
                                                   const int* __restrict__ fwd) {
    int t = blockIdx.x * blockDim.x + threadIdx.x;
    if (t >= CSR_TOTAL) return;
    int slot, e; const int *es, *ed;
    edge_decode(t, ei, inner, fwd, slot, es, ed, e);
    atomicAdd(&g_deg[slot * N_NODES + ed[e]], 1);
}

__global__ __launch_bounds__(256) void k_dinv() {
    int i = blockIdx.x * blockDim.x + threadIdx.x;
    if (i < NSETS * N_NODES) g_dinv[i] = rsqrtf(1.0f + (float)g_deg[i]);
}

__global__ __launch_bounds__(256) void k_wt(const float* __restrict__ W, int which) {
    int t = blockIdx.x * blockDim.x + threadIdx.x;
    if (t >= 288 * 256) return;
    int k = t >> 8, n = t & 255;
    int kb = k >> 5, kq = k & 31, quad = kq >> 3, ke = kq & 7;
    int nt = n >> 4, m = n & 15, lane = quad * 16 + m;
    int idx = which * WFSZ + (kb * 16 + nt) * 512 + lane * 8 + ke;
    float w = W[t];
    unsigned short h = f2bf(w);
    unsigned short l = f2bf(w - bf2f(h));
    g_Wfh[idx] = h;
    g_Wfl[idx] = l;
}

// ---- hierarchical scan ----

__global__ __launch_bounds__(256) void k_scan_a() {
    int b = blockIdx.x;
    int set = b / NCHK, ch = b % NCHK;
    const int* deg = g_deg + (size_t)set * N_NODES;
    int base = ch * PCHUNK + threadIdx.x * 16;
    int s = 0;
#pragma unroll
    for (int j = 0; j < 16; j++) {
        int id = base + j;
        if (id < N_NODES) s += deg[id];
    }
    __shared__ int sm[256];
    sm[threadIdx.x] = s;
    __syncthreads();
    for (int o = 128; o > 0; o >>= 1) {
        if (threadIdx.x < o) sm[threadIdx.x] += sm[threadIdx.x + o];
        __syncthreads();
    }
    if (threadIdx.x == 0) g_part[b] = sm[0];
}

__global__ __launch_bounds__(1024) void k_scan_b() {
    int wv = threadIdx.x >> 6, lane = threadIdx.x & 63;
    if (wv >= NSETS) return;
    int v = (lane < NCHK) ? g_part[wv * NCHK + lane] : 0;
    int orig = v;
    for (int o = 1; o < 32; o <<= 1) {
        int u = __shfl_up(v, o);
        if (lane >= o) v += u;
    }
    if (lane < NCHK) g_part[wv * NCHK + lane] = v - orig;
}

__global__ __launch_bounds__(256) void k_scan_c() {
    int b = blockIdx.x;
    int set = b / NCHK, ch = b % NCHK;
    const int* deg = g_deg + (size_t)set * N_NODES;
    int* off = g_off + (size_t)set * (N_NODES + 1);
    int* cur = g_cur + (size_t)set * N_NODES;
    int t = threadIdx.x;
    int base = ch * PCHUNK + t * 16;
    int v[16];
    int s = 0;
#pragma unroll
    for (int j = 0; j < 16; j++) {
        int id = base + j;
        v[j] = (id < N_NODES) ? deg[id] : 0;
        s += v[j];
    }
    __shared__ int sm[256];
    sm[t] = s;
    __syncthreads();
    for (int o = 1; o < 256; o <<= 1) {
        int u = (t >= o) ? sm[t - o] : 0;
        __syncthreads();
        sm[t] += u;
        __syncthreads();
    }
    int run = g_part[b] + sm[t] - s;
#pragma unroll
    for (int j = 0; j < 16; j++) {
        int id = base + j;
        if (id < N_NODES) { off[id] = run; cur[id] = run; }
        run += v[j];
    }
    if (ch == NCHK - 1 && t == 255) off[N_NODES] = (set == 0) ? NE_MAIN : NE_SET;
}

__global__ __launch_bounds__(256) void k_fill_all(const int* __restrict__ ei,
                                                  const int* __restrict__ inner,
                                                  const int* __restrict__ fwd) {
    int t = blockIdx.x * blockDim.x + threadIdx.x;
    if (t >= CSR_TOTAL) return;
    int slot, e; const int *es, *ed;
    edge_decode(t, ei, inner, fwd, slot, es, ed, e);
    int s = es[e], d = ed[e];
    int pos = atomicAdd(&g_cur[slot * N_NODES + d], 1);
    g_csrs[csr_base(slot) + pos] = s;
}

__global__ __launch_bounds__(256) void k_lists(const int* __restrict__ layers) {
    __shared__ int lcnt[4];
    __shared__ int lbase[4];
    int i = blockIdx.x * blockDim.x + threadIdx.x;
    if (threadIdx.x < 4) lcnt[threadIdx.x] = 0;
    __syncthreads();
    int l = -1, p = 0;
    if (i < N_NODES) {
        l = layers[i];
        p = atomicAdd(&lcnt[l], 1);
    }
    __syncthreads();
    if (threadIdx.x < 4) lbase[threadIdx.x] = atomicAdd(&g_cnt[threadIdx.x], lcnt[threadIdx.x]);
    __syncthreads();
    if (l >= 0) g_lists[l * N_NODES + lbase[l] + p] = i;
}

// ----------------------------- conv0 (K=16) -----------------------------

__global__ __launch_bounds__(256) void k_gather16(const float* __restrict__ xin) {
    int g = blockIdx.x * blockDim.x + threadIdx.x;
    int i = g >> 4, lane = g & 15;
    if (i >= N_NODES) return;
    float dv = g_dinv[i];
    float acc = dv * dv * xin[i * 16 + lane];
    int e0 = g_off[i], e1 = g_off[i + 1];
    for (int e = e0; e < e1; e++) {
        int s = g_csrs[e];
        acc += g_dinv[s] * dv * xin[s * 16 + lane];
    }
    g_agg16[i * 16 + lane] = acc;
}

__global__ __launch_bounds__(256) void k_gemm0(const float* __restrict__ W,
                                               const float* __restrict__ bias) {
    __shared__ float a[128];
    int base = blockIdx.x * 8;
    int t = threadIdx.x;
    if (t < 128) a[t] = g_agg16[base * 16 + t];
    __syncthreads();
    float bb = bias[t];
    for (int r = 0; r < 8; r++) {
        float acc = bb;
#pragma unroll
        for (int k = 0; k < 16; k++) acc += a[r * 16 + k] * W[k * 256 + t];
        g_x[(size_t)(base + r) * 256 + t] = f2bf(acc);
    }
}

// -------- fused conv: 16-lane-per-row gather -> LDS hi/lo -> 3-term MFMA --------
// block: 32 rows, 4 waves. Phase 1: each wave = 4 groups of 16 lanes, each group
// gathers 2 rows (4 independent chains/wave). Phase 2: wave w -> col stripe w*64.

__global__ __launch_bounds__(256, 4) void k_conv(int slot, int which,
                                                 const float* __restrict__ bias,
                                                 const int* __restrict__ layersp,
                                                 int layer, int topi) {
    int count = (layer >= 0) ? g_cnt[layer] : N_NODES;
    int base = blockIdx.x * 32;
    if (base >= count) return;
    const unsigned short* Wfh = g_Wfh + (size_t)which * WFSZ;
    const unsigned short* Wfl = g_Wfl + (size_t)which * WFSZ;
    unsigned short* out = topi ? g_pi : g_x;

    __shared__ unsigned short lds_h[32 * ASTR];
    __shared__ unsigned short lds_l[32 * ASTR];
    __shared__ int rows_s[32];
    int t = threadIdx.x;
    if (t < 32) {
        int r = base + t;
        rows_s[t] = (r < count) ? ((layer >= 0) ? g_lists[layer * N_NODES + r] : r) : -1;
    }
    __syncthreads();

    int wv = t >> 6, lane = t & 63;
    int grp = lane >> 4, gl = lane & 15;

    // ---- phase 1: each 16-lane group gathers 2 rows ----
    const float* dinv_s = g_dinv + (size_t)slot * N_NODES;
    const int* offp = g_off + (size_t)slot * (N_NODES + 1);
    int cb = csr_base(slot);
    for (int rr = 0; rr < 2; rr++) {
        int lr = wv * 8 + grp * 2 + rr;
        int row = rows_s[lr];
        float acc0[8], acc1[8], accf[8];
#pragma unroll
        for (int j = 0; j < 8; j++) { acc0[j] = 0.f; acc1[j] = 0.f; accf[j] = 0.f; }
        if (row >= 0) {
            float dvr = dinv_s[row];
            float d2 = dvr * dvr;
            us8_t u0 = *(const us8_t*)&g_x[(size_t)row * 256 + gl * 8];
            us8_t u1 = *(const us8_t*)&g_x[(size_t)row * 256 + 128 + gl * 8];
#pragma unroll
            for (int j = 0; j < 8; j++) { acc0[j] = d2 * bf2f(u0[j]); acc1[j] = d2 * bf2f(u1[j]); }
            if (gl < 4) {
                us8_t uf = *(const us8_t*)&g_fsb[(size_t)row * 32 + gl * 8];
#pragma unroll
                for (int j = 0; j < 8; j++) accf[j] = d2 * bf2f(uf[j]);
            }
            int e0 = offp[row] + cb, e1e = offp[row + 1] + cb;
            int e = e0;
            for (; e + 1 < e1e; e += 2) {   // batch 2 edges' loads for MLP
                int sa = g_csrs[e], sb = g_csrs[e + 1];
                float na = dinv_s[sa] * dvr;
                float nb = dinv_s[sb] * dvr;
                us8_t va0 = *(const us8_t*)&g_x[(size_t)sa * 256 + gl * 8];
                us8_t va1 = *(const us8_t*)&g_x[(size_t)sa * 256 + 128 + gl * 8];
                us8_t vb0 = *(const us8_t*)&g_x[(size_t)sb * 256 + gl * 8];
                us8_t vb1 = *(const us8_t*)&g_x[(size_t)sb * 256 + 128 + gl * 8];
#pragma unroll
                for (int j = 0; j < 8; j++) {
                    acc0[j] += na * bf2f(va0[j]); acc1[j] += na * bf2f(va1[j]);
                    acc0[j] += nb * bf2f(vb0[j]); acc1[j] += nb * bf2f(vb1[j]);
                }
                if (gl < 4) {
                    us8_t fa = *(const us8_t*)&g_fsb[(size_t)sa * 32 + gl * 8];
                    us8_t fb = *(const us8_t*)&g_fsb[(size_t)sb * 32 + gl * 8];
#pragma unroll
                    for (int j = 0; j < 8; j++)
                        accf[j] += na * bf2f(fa[j]) + nb * bf2f(fb[j]);
                }
            }
            if (e < e1e) {
                int sa = g_csrs[e];
                float na = dinv_s[sa] * dvr;
                us8_t va0 = *(const us8_t*)&g_x[(size_t)sa * 256 + gl * 8];
                us8_t va1 = *(const us8_t*)&g_x[(size_t)sa * 256 + 128 + gl * 8];
#pragma unroll
                for (int j = 0; j < 8; j++) {
                    acc0[j] += na * bf2f(va0[j]); acc1[j] += na * bf2f(va1[j]);
                }
                if (gl < 4) {
                    us8_t fa = *(const us8_t*)&g_fsb[(size_t)sa * 32 + gl * 8];
#pragma unroll
                    for (int j = 0; j < 8; j++) accf[j] += na * bf2f(fa[j]);
                }
            }
        }
        us8_t h0, l0, h1, l1;
#pragma unroll
        for (int j = 0; j < 8; j++) {
            h0[j] = f2bf(acc0[j]); l0[j] = f2bf(acc0[j] - bf2f(h0[j]));
            h1[j] = f2bf(acc1[j]); l1[j] = f2bf(acc1[j] - bf2f(h1[j]));
        }
        *(us8_t*)&lds_h[lr * ASTR + gl * 8] = h0;
        *(us8_t*)&lds_h[lr * ASTR + 128 + gl * 8] = h1;
        *(us8_t*)&lds_l[lr * ASTR + gl * 8] = l0;
        *(us8_t*)&lds_l[lr * ASTR + 128 + gl * 8] = l1;
        if (gl < 4) {
            us8_t hf, lf;
#pragma unroll
            for (int j = 0; j < 8; j++) {
                hf[j] = f2bf(accf[j]); lf[j] = f2bf(accf[j] - bf2f(hf[j]));
            }
            *(us8_t*)&lds_h[lr * ASTR + 256 + gl * 8] = hf;
            *(us8_t*)&lds_l[lr * ASTR + 256 + gl * 8] = lf;
        }
    }
    __syncthreads();

    // ---- phase 2: MFMA (2 row tiles x 4 col tiles per wave) ----
    int m = lane & 15, quad = lane >> 4;
    int n0 = wv * 64;
    f4_t acc2[2][4];
#pragma unroll
    for (int rt = 0; rt < 2; rt++)
#pragma unroll
        for (int ct = 0; ct < 4; ct++) acc2[rt][ct] = (f4_t){0.f, 0.f, 0.f, 0.f};

    for (int kb = 0; kb < 9; kb++) {
        int k0 = kb * 32;
        bf8_t ah0 = *(const bf8_t*)&lds_h[m * ASTR + k0 + quad * 8];
        bf8_t al0 = *(const bf8_t*)&lds_l[m * ASTR + k0 + quad * 8];
        bf8_t ah1 = *(const bf8_t*)&lds_h[(16 + m) * ASTR + k0 + quad * 8];
        bf8_t al1 = *(const bf8_t*)&lds_l[(16 + m) * ASTR + k0 + quad * 8];
#pragma unroll
        for (int ct = 0; ct < 4; ct++) {
            int nt = wv * 4 + ct;
            const bf8_t bh = *(const bf8_t*)&Wfh[(kb * 16 + nt) * 512 + lane * 8];
            const bf8_t bl = *(const bf8_t*)&Wfl[(kb * 16 + nt) * 512 + lane * 8];
            acc2[0][ct] = __builtin_amdgcn_mfma_f32_16x16x32_bf16(ah0, bh, acc2[0][ct], 0, 0, 0);
            acc2[0][ct] = __builtin_amdgcn_mfma_f32_16x16x32_bf16(al0, bh, acc2[0][ct], 0, 0, 0);
            acc2[0][ct] = __builtin_amdgcn_mfma_f32_16x16x32_bf16(ah0, bl, acc2[0][ct], 0, 0, 0);
            acc2[1][ct] = __builtin_amdgcn_mfma_f32_16x16x32_bf16(ah1, bh, acc2[1][ct], 0, 0, 0);
            acc2[1][ct] = __builtin_amdgcn_mfma_f32_16x16x32_bf16(al1, bh, acc2[1][ct], 0, 0, 0);
            acc2[1][ct] = __builtin_amdgcn_mfma_f32_16x16x32_bf16(ah1, bl, acc2[1][ct], 0, 0, 0);
        }
    }
    // epilogue: C/D layout col=lane&15, row=quad*4+reg; full conv dual-writes l3 rows
#pragma unroll
    for (int rt = 0; rt < 2; rt++) {
#pragma unroll
        for (int r = 0; r < 4; r++) {
            int row = rows_s[rt * 16 + quad * 4 + r];
            if (row < 0) continue;
            int dual = topi && (layersp[row] == 3);
#pragma unroll
            for (int ct = 0; ct < 4; ct++) {
                int n = n0 + ct * 16 + m;
                unsigned short v = f2bf(acc2[rt][ct][r] + bias[n]);
                out[(size_t)row * 256 + n] = v;
                if (dual) g_x[(size_t)row * 256 + n] = v;
            }
        }
    }
}

// ----------------------------- misc -----------------------------

__global__ __launch_bounds__(256) void k_copy_rows(int layer) {
    int w = (blockIdx.x * blockDim.x + threadIdx.x) >> 5;
    int lane = threadIdx.x & 31;
    if (w >= g_cnt[layer]) return;
    int i = g_lists[layer * N_NODES + w];
    *(uint4*)(g_x + (size_t)i * 256 + lane * 8) =
        *(const uint4*)(g_pi + (size_t)i * 256 + lane * 8);
}

__global__ __launch_bounds__(256) void k_relu() {
    int i = blockIdx.x * blockDim.x + threadIdx.x;
    if (i >= N_NODES * 32) return;
    ushort4 a = ((ushort4*)g_x)[i * 2];
    ushort4 b = ((ushort4*)g_x)[i * 2 + 1];
    a.x = (a.x & 0x8000) ? 0 : a.x; a.y = (a.y & 0x8000) ? 0 : a.y;
    a.z = (a.z & 0x8000) ? 0 : a.z; a.w = (a.w & 0x8000) ? 0 : a.w;
    b.x = (b.x & 0x8000) ? 0 : b.x; b.y = (b.y & 0x8000) ? 0 : b.y;
    b.z = (b.z & 0x8000) ? 0 : b.z; b.w = (b.w & 0x8000) ? 0 : b.w;
    ((ushort4*)g_x)[i * 2] = a;
    ((ushort4*)g_x)[i * 2 + 1] = b;
}

// pool with fused final ReLU
__global__ __launch_bounds__(256) void k_pool(const int* __restrict__ batch) {
    __shared__ int bs[128];
    int i0 = blockIdx.x * 128;
    if (threadIdx.x < 128) {
        int i = i0 + threadIdx.x;
        bs[threadIdx.x] = (i < N_NODES) ? batch[i] : -1;
    }
    __syncthreads();
    int c = threadIdx.x;
    int lim = min(128, N_NODES - i0);
    float acc = 0.f;
    int cur = bs[0];
    for (int ii = 0; ii < lim; ii++) {
        int g = bs[ii];
        if (g != cur) { atomicAdd(&g_pooled[cur * 256 + c], acc); acc = 0.f; cur = g; }
        acc += fmaxf(bf2f(g_x[(size_t)(i0 + ii) * 256 + c]), 0.f);
    }
    atomicAdd(&g_pooled[cur * 256 + c], acc);
}

__global__ void k_final(const float* __restrict__ W_lin, const float* __restrict__ b_lin,
                        float* __restrict__ out) {
    int g = blockIdx.x;
    int lane = threadIdx.x;
    float4 p = *(const float4*)(g_pooled + g * 256 + lane * 4);
    float4 w = *(const float4*)(W_lin + lane * 4);
    float s = p.x * w.x + p.y * w.y + p.z * w.z + p.w * w.w;
    for (int o = 32; o > 0; o >>= 1) s += __shfl_down(s, o);
    if (lane == 0) out[g] = s + b_lin[0];
}

// ----------------------------- host -----------------------------

extern "C" void kernel_launch(void* const* d_in, const int* in_sizes, int n_in,
                              void* d_out, int out_size, void* d_ws, size_t ws_size,
                              hipStream_t stream) {
    const float* xin   = (const float*)d_in[0];
    const float* fs    = (const float*)d_in[1];
    const int* ei      = (const int*)d_in[2];
    const int* inner   = (const int*)d_in[3];
    const int* fwd     = (const int*)d_in[4];
    const int* layers  = (const int*)d_in[6];
    const int* batch   = (const int*)d_in[7];
    const float* W_up  = (const float*)d_in[8];
    const float* b_up  = (const float*)d_in[9];
    const float* W_in  = (const float*)d_in[10];
    const float* b_in  = (const float*)d_in[11];
    const float* W_fw  = (const float*)d_in[12];
    const float* b_fw  = (const float*)d_in[13];
    const float* W_lin = (const float*)d_in[14];
    const float* b_lin = (const float*)d_in[15];
    float* out = (float*)d_out;

    // --- CSR build + weight split + fs bf16 copy ---
    k_init<<<(NSETS * N_NODES + 255) / 256, 256, 0, stream>>>();
    k_fsb<<<(N_NODES * 32 + 255) / 256, 256, 0, stream>>>(fs);
    k_wt<<<(288 * 256 + 255) / 256, 256, 0, stream>>>(W_in, 0);
    k_wt<<<(288 * 256 + 255) / 256, 256, 0, stream>>>(W_fw, 1);
    k_count_all<<<(CSR_TOTAL + 255) / 256, 256, 0, stream>>>(ei, inner, fwd);
    k_dinv<<<(NSETS * N_NODES + 255) / 256, 256, 0, stream>>>();
    k_scan_a<<<NSETS * NCHK, 256, 0, stream>>>();
    k_scan_b<<<1, 1024, 0, stream>>>();
    k_scan_c<<<NSETS * NCHK, 256, 0, stream>>>();
    k_fill_all<<<(CSR_TOTAL + 255) / 256, 256, 0, stream>>>(ei, inner, fwd);
    k_lists<<<(N_NODES + 255) / 256, 256, 0, stream>>>(layers);

    // --- conv0 ---
    k_gather16<<<(N_NODES * 16 + 255) / 256, 256, 0, stream>>>(xin);
    k_gemm0<<<N_NODES / 8, 256, 0, stream>>>(W_up, b_up);

    auto conv = [&](int slot, int which, const float* bias, int layer, int topi) {
        k_conv<<<(N_NODES + 31) / 32, 256, 0, stream>>>(slot, which, bias, layers, layer, topi);
    };

    for (int p = 0; p < NPROP; p++) {
        for (int il = 0; il < NLAYERS; il++) {
            if (il < NLAYERS - 1) {
                conv(1 + il, 0, b_in, il, 0);
                conv(5 + il, 1, b_fw, il + 1, 0);   // il=3 fwd is dead
            } else {
                conv(1 + il, 0, b_in, -1, 1);       // full -> pi, dual-writes x l3 rows
            }
        }
        k_relu<<<(N_NODES * 32 + 255) / 256, 256, 0, stream>>>();
        for (int il = NLAYERS - 1; il >= 0; il--) {
            if (il >= 1) k_copy_rows<<<12500, 256, 0, stream>>>(il - 1);
            conv(1 + il, 0, b_in, il, 0);
        }
        if (p < NPROP - 1)
            k_relu<<<(N_NODES * 32 + 255) / 256, 256, 0, stream>>>();
    }

    k_pool<<<(N_NODES + 127) / 128, 256, 0, stream>>>(batch);
    k_final<<<NGRAPHS, 64, 0, stream>>>(W_lin, b_lin, out);
}

// Round 12
// 1365.700 us; speedup vs baseline: 1.7103x; 1.1041x over previous
//
#include <hip/hip_runtime.h>

#define N_NODES 100000
#define NLAYERS 4
#define NPROP 2
#define NGRAPHS 50
#define NE_MAIN 400000
#define NE_SET 300000
#define NSETS 9            // 0=main, 1..4=inner, 5..8=fwd (slot 8 unused/dead)
#define CSR_TOTAL (NE_MAIN + 8 * NE_SET)
#define ASTR 296           // LDS agg row stride (shorts)
#define WFSZ (9 * 16 * 512)  // fragment-ordered W
#define PCHUNK 4096
#define NCHK 25

typedef __attribute__((ext_vector_type(8))) short bf8_t;
typedef __attribute__((ext_vector_type(8))) unsigned short us8_t;
typedef __attribute__((ext_vector_type(4))) float f4_t;

// ---------------- static device scratch ----------------
__device__ __align__(16) unsigned short g_x[(size_t)N_NODES * 256];
__device__ __align__(16) unsigned short g_pi[(size_t)N_NODES * 256];
__device__ __align__(16) unsigned short g_fsb[(size_t)N_NODES * 32];
__device__ __align__(16) float g_agg16[(size_t)N_NODES * 16];
__device__ __align__(16) float g_dinv[NSETS * N_NODES];
__device__ __align__(16) float g_pooled[NGRAPHS * 256];
__device__ __align__(16) unsigned short g_Wfh[2 * WFSZ];
__device__ __align__(16) unsigned short g_Wfl[2 * WFSZ];
__device__ int g_deg[NSETS * N_NODES];    // full degrees (for dinv)
__device__ int g_degf[NSETS * N_NODES];   // filtered degrees (for CSR offsets)
__device__ int g_cur[NSETS * N_NODES];
__device__ int g_off[NSETS * (N_NODES + 1)];
__device__ int g_part[NSETS * NCHK];
__device__ int g_csrs[CSR_TOTAL];   // src only; nrm recomputed from dinv
__device__ int g_cnt[4];
__device__ int g_lists[NLAYERS * N_NODES];

__host__ __device__ inline int csr_base(int slot) {
    return slot == 0 ? 0 : NE_MAIN + (slot - 1) * NE_SET;
}

__device__ inline unsigned short f2bf(float f) {
    unsigned u = __float_as_uint(f);
    return (unsigned short)((u + 0x7fffu + ((u >> 16) & 1u)) >> 16);
}
__device__ inline float bf2f(unsigned short b) {
    return __uint_as_float(((unsigned)b) << 16);
}

__device__ inline void edge_decode(int t, const int* ei, const int* inner, const int* fwd,
                                   int& slot, const int*& es, const int*& ed, int& e) {
    if (t < NE_MAIN) {
        slot = 0; e = t; es = ei; ed = ei + NE_MAIN;
    } else {
        int r = t - NE_MAIN;
        int grp = r / NE_SET;
        e = r - grp * NE_SET;
        slot = 1 + grp;
        const int* base = (grp < 4) ? (inner + grp * 2 * NE_SET)
                                    : (fwd + (grp - 4) * 2 * NE_SET);
        es = base; ed = base + NE_SET;
    }
}

// CSR filter: which edges can ever be read by a conv on this slot?
// slot 0 (main): all. slots 1..3 (inner0..2): masked conv layer il only.
// slot 4 (inner3): full (full conv). slots 5..7 (fwd0..2): masked layer il+1.
// slot 8 (fwd3): dead.
__device__ inline int csr_keep(int slot, int ld) {
    if (slot == 0 || slot == 4) return 1;
    if (slot <= 3) return ld == slot - 1;
    if (slot <= 7) return ld == slot - 4;
    return 0;
}

// ----------------------------- setup -----------------------------

__global__ __launch_bounds__(256) void k_init() {
    int i = blockIdx.x * blockDim.x + threadIdx.x;
    if (i < NSETS * N_NODES) { g_deg[i] = 0; g_degf[i] = 0; }
    if (i < NGRAPHS * 256) g_pooled[i] = 0.f;
    if (i < 4) g_cnt[i] = 0;
}

__global__ __launch_bounds__(256) void k_fsb(const float* __restrict__ fs) {
    int i = blockIdx.x * blockDim.x + threadIdx.x;
    if (i < N_NODES * 32) g_fsb[i] = f2bf(fs[i]);
}

__global__ __launch_bounds__(256) void k_count_all(const int* __restrict__ ei,
                                                   const int* __restrict__ inner,
                                                   const int* __restrict__ fwd,
                                                   const int* __restrict__ layers) {
    int t = blockIdx.x * blockDim.x + threadIdx.x;
    if (t >= CSR_TOTAL - NE_SET) return;   // skip slot 8 (dead)
    int slot, e; const int *es, *ed;
    edge_decode(t, ei, inner, fwd, slot, es, ed, e);
    int d = ed[e];
    atomicAdd(&g_deg[slot * N_NODES + d], 1);              // full degree (norm)
    if (slot == 0 || slot == 4 || csr_keep(slot, layers[d]))
        atomicAdd(&g_degf[slot * N_NODES + d], 1);         // filtered (offsets)
}

__global__ __launch_bounds__(256) void k_dinv() {
    int i = blockIdx.x * blockDim.x + threadIdx.x;
    if (i < NSETS * N_NODES) g_dinv[i] = rsqrtf(1.0f + (float)g_deg[i]);
}

__global__ __launch_bounds__(256) void k_wt(const float* __restrict__ W, int which) {
    int t = blockIdx.x * blockDim.x + threadIdx.x;
    if (t >= 288 * 256) return;
    int k = t >> 8, n = t & 255;
    int kb = k >> 5, kq = k & 31, quad = kq >> 3, ke = kq & 7;
    int nt = n >> 4, m = n & 15, lane = quad * 16 + m;
    int idx = which * WFSZ + (kb * 16 + nt) * 512 + lane * 8 + ke;
    float w = W[t];
    unsigned short h = f2bf(w);
    unsigned short l = f2bf(w - bf2f(h));
    g_Wfh[idx] = h;
    g_Wfl[idx] = l;
}

// ---- hierarchical scan over filtered degrees ----

__global__ __launch_bounds__(256) void k_scan_a() {
    int b = blockIdx.x;
    int set = b / NCHK, ch = b % NCHK;
    const int* deg = g_degf + (size_t)set * N_NODES;
    int base = ch * PCHUNK + threadIdx.x * 16;
    int s = 0;
#pragma unroll
    for (int j = 0; j < 16; j++) {
        int id = base + j;
        if (id < N_NODES) s += deg[id];
    }
    __shared__ int sm[256];
    sm[threadIdx.x] = s;
    __syncthreads();
    for (int o = 128; o > 0; o >>= 1) {
        if (threadIdx.x < o) sm[threadIdx.x] += sm[threadIdx.x + o];
        __syncthreads();
    }
    if (threadIdx.x == 0) g_part[b] = sm[0];
}

__global__ __launch_bounds__(1024) void k_scan_b() {
    int wv = threadIdx.x >> 6, lane = threadIdx.x & 63;
    if (wv >= NSETS) return;
    int v = (lane < NCHK) ? g_part[wv * NCHK + lane] : 0;
    int orig = v;
    for (int o = 1; o < 32; o <<= 1) {
        int u = __shfl_up(v, o);
        if (lane >= o) v += u;
    }
    if (lane < NCHK) g_part[wv * NCHK + lane] = v - orig;
}

__global__ __launch_bounds__(256) void k_scan_c() {
    int b = blockIdx.x;
    int set = b / NCHK, ch = b % NCHK;
    const int* deg = g_degf + (size_t)set * N_NODES;
    int* off = g_off + (size_t)set * (N_NODES + 1);
    int* cur = g_cur + (size_t)set * N_NODES;
    int t = threadIdx.x;
    int base = ch * PCHUNK + t * 16;
    int v[16];
    int s = 0;
#pragma unroll
    for (int j = 0; j < 16; j++) {
        int id = base + j;
        v[j] = (id < N_NODES) ? deg[id] : 0;
        s += v[j];
    }
    __shared__ int sm[256];
    sm[t] = s;
    __syncthreads();
    for (int o = 1; o < 256; o <<= 1) {
        int u = (t >= o) ? sm[t - o] : 0;
        __syncthreads();
        sm[t] += u;
        __syncthreads();
    }
    int run = g_part[b] + sm[t] - s;
#pragma unroll
    for (int j = 0; j < 16; j++) {
        int id = base + j;
        if (id < N_NODES) { off[id] = run; cur[id] = run; }
        run += v[j];
    }
    // off[N_NODES] never read by convs (rows use off[row+1] with row<N via degf sums)
}

__global__ __launch_bounds__(256) void k_fill_all(const int* __restrict__ ei,
                                                  const int* __restrict__ inner,
                                                  const int* __restrict__ fwd,
                                                  const int* __restrict__ layers) {
    int t = blockIdx.x * blockDim.x + threadIdx.x;
    if (t >= CSR_TOTAL - NE_SET) return;   // skip slot 8
    int slot, e; const int *es, *ed;
    edge_decode(t, ei, inner, fwd, slot, es, ed, e);
    int d = ed[e];
    if (!(slot == 0 || slot == 4 || csr_keep(slot, layers[d]))) return;
    int s = es[e];
    int pos = atomicAdd(&g_cur[slot * N_NODES + d], 1);
    g_csrs[csr_base(slot) + pos] = s;
}

__global__ __launch_bounds__(256) void k_lists(const int* __restrict__ layers) {
    __shared__ int lcnt[4];
    __shared__ int lbase[4];
    int i = blockIdx.x * blockDim.x + threadIdx.x;
    if (threadIdx.x < 4) lcnt[threadIdx.x] = 0;
    __syncthreads();
    int l = -1, p = 0;
    if (i < N_NODES) {
        l = layers[i];
        p = atomicAdd(&lcnt[l], 1);
    }
    __syncthreads();
    if (threadIdx.x < 4) lbase[threadIdx.x] = atomicAdd(&g_cnt[threadIdx.x], lcnt[threadIdx.x]);
    __syncthreads();
    if (l >= 0) g_lists[l * N_NODES + lbase[l] + p] = i;
}

// ----------------------------- conv0 (K=16) -----------------------------

__global__ __launch_bounds__(256) void k_gather16(const float* __restrict__ xin) {
    int g = blockIdx.x * blockDim.x + threadIdx.x;
    int i = g >> 4, lane = g & 15;
    if (i >= N_NODES) return;
    float dv = g_dinv[i];
    float acc = dv * dv * xin[i * 16 + lane];
    int e0 = g_off[i], e1 = g_off[i] + g_degf[i];
    for (int e = e0; e < e1; e++) {
        int s = g_csrs[e];
        acc += g_dinv[s] * dv * xin[s * 16 + lane];
    }
    g_agg16[i * 16 + lane] = acc;
}

__global__ __launch_bounds__(256) void k_gemm0(const float* __restrict__ W,
                                               const float* __restrict__ bias) {
    __shared__ float a[128];
    int base = blockIdx.x * 8;
    int t = threadIdx.x;
    if (t < 128) a[t] = g_agg16[base * 16 + t];
    __syncthreads();
    float bb = bias[t];
    for (int r = 0; r < 8; r++) {
        float acc = bb;
#pragma unroll
        for (int k = 0; k < 16; k++) acc += a[r * 16 + k] * W[k * 256 + t];
        g_x[(size_t)(base + r) * 256 + t] = f2bf(acc);
    }
}

// -------- fused conv: 16-lane-per-row gather -> LDS hi/lo -> 3-term MFMA --------

__global__ __launch_bounds__(256, 4) void k_conv(int slot, int which,
                                                 const float* __restrict__ bias,
                                                 int layer, int topi) {
    int count = (layer >= 0) ? g_cnt[layer] : N_NODES;
    int base = blockIdx.x * 32;
    if (base >= count) return;
    const unsigned short* Wfh = g_Wfh + (size_t)which * WFSZ;
    const unsigned short* Wfl = g_Wfl + (size_t)which * WFSZ;
    unsigned short* out = topi ? g_pi : g_x;

    __shared__ unsigned short lds_h[32 * ASTR];
    __shared__ unsigned short lds_l[32 * ASTR];
    __shared__ int rows_s[32];
    int t = threadIdx.x;
    if (t < 32) {
        int r = base + t;
        rows_s[t] = (r < count) ? ((layer >= 0) ? g_lists[layer * N_NODES + r] : r) : -1;
    }
    __syncthreads();

    int wv = t >> 6, lane = t & 63;
    int grp = lane >> 4, gl = lane & 15;

    const float* dinv_s = g_dinv + (size_t)slot * N_NODES;
    const int* offp = g_off + (size_t)slot * (N_NODES + 1);
    const int* degfp = g_degf + (size_t)slot * N_NODES;
    int cb = csr_base(slot);
    for (int rr = 0; rr < 2; rr++) {
        int lr = wv * 8 + grp * 2 + rr;
        int row = rows_s[lr];
        float acc0[8], acc1[8], accf[8];
#pragma unroll
        for (int j = 0; j < 8; j++) { acc0[j] = 0.f; acc1[j] = 0.f; accf[j] = 0.f; }
        if (row >= 0) {
            float dvr = dinv_s[row];
            float d2 = dvr * dvr;
            us8_t u0 = *(const us8_t*)&g_x[(size_t)row * 256 + gl * 8];
            us8_t u1 = *(const us8_t*)&g_x[(size_t)row * 256 + 128 + gl * 8];
#pragma unroll
            for (int j = 0; j < 8; j++) { acc0[j] = d2 * bf2f(u0[j]); acc1[j] = d2 * bf2f(u1[j]); }
            if (gl < 4) {
                us8_t uf = *(const us8_t*)&g_fsb[(size_t)row * 32 + gl * 8];
#pragma unroll
                for (int j = 0; j < 8; j++) accf[j] = d2 * bf2f(uf[j]);
            }
            int e0 = offp[row] + cb, e1e = e0 + degfp[row];
            int e = e0;
            for (; e + 1 < e1e; e += 2) {
                int sa = g_csrs[e], sb = g_csrs[e + 1];
                float na = dinv_s[sa] * dvr;
                float nb = dinv_s[sb] * dvr;
                us8_t va0 = *(const us8_t*)&g_x[(size_t)sa * 256 + gl * 8];
                us8_t va1 = *(const us8_t*)&g_x[(size_t)sa * 256 + 128 + gl * 8];
                us8_t vb0 = *(const us8_t*)&g_x[(size_t)sb * 256 + gl * 8];
                us8_t vb1 = *(const us8_t*)&g_x[(size_t)sb * 256 + 128 + gl * 8];
#pragma unroll
                for (int j = 0; j < 8; j++) {
                    acc0[j] += na * bf2f(va0[j]); acc1[j] += na * bf2f(va1[j]);
                    acc0[j] += nb * bf2f(vb0[j]); acc1[j] += nb * bf2f(vb1[j]);
                }
                if (gl < 4) {
                    us8_t fa = *(const us8_t*)&g_fsb[(size_t)sa * 32 + gl * 8];
                    us8_t fb = *(const us8_t*)&g_fsb[(size_t)sb * 32 + gl * 8];
#pragma unroll
                    for (int j = 0; j < 8; j++)
                        accf[j] += na * bf2f(fa[j]) + nb * bf2f(fb[j]);
                }
            }
            if (e < e1e) {
                int sa = g_csrs[e];
                float na = dinv_s[sa] * dvr;
                us8_t va0 = *(const us8_t*)&g_x[(size_t)sa * 256 + gl * 8];
                us8_t va1 = *(const us8_t*)&g_x[(size_t)sa * 256 + 128 + gl * 8];
#pragma unroll
                for (int j = 0; j < 8; j++) {
                    acc0[j] += na * bf2f(va0[j]); acc1[j] += na * bf2f(va1[j]);
                }
                if (gl < 4) {
                    us8_t fa = *(const us8_t*)&g_fsb[(size_t)sa * 32 + gl * 8];
#pragma unroll
                    for (int j = 0; j < 8; j++) accf[j] += na * bf2f(fa[j]);
                }
            }
        }
        us8_t h0, l0, h1, l1;
#pragma unroll
        for (int j = 0; j < 8; j++) {
            h0[j] = f2bf(acc0[j]); l0[j] = f2bf(acc0[j] - bf2f(h0[j]));
            h1[j] = f2bf(acc1[j]); l1[j] = f2bf(acc1[j] - bf2f(h1[j]));
        }
        *(us8_t*)&lds_h[lr * ASTR + gl * 8] = h0;
        *(us8_t*)&lds_h[lr * ASTR + 128 + gl * 8] = h1;
        *(us8_t*)&lds_l[lr * ASTR + gl * 8] = l0;
        *(us8_t*)&lds_l[lr * ASTR + 128 + gl * 8] = l1;
        if (gl < 4) {
            us8_t hf, lf;
#pragma unroll
            for (int j = 0; j < 8; j++) {
                hf[j] = f2bf(accf[j]); lf[j] = f2bf(accf[j] - bf2f(hf[j]));
            }
            *(us8_t*)&lds_h[lr * ASTR + 256 + gl * 8] = hf;
            *(us8_t*)&lds_l[lr * ASTR + 256 + gl * 8] = lf;
        }
    }
    __syncthreads();

    // ---- phase 2: MFMA ----
    int m = lane & 15, quad = lane >> 4;
    int n0 = wv * 64;
    f4_t acc2[2][4];
#pragma unroll
    for (int rt = 0; rt < 2; rt++)
#pragma unroll
        for (int ct = 0; ct < 4; ct++) acc2[rt][ct] = (f4_t){0.f, 0.f, 0.f, 0.f};

    for (int kb = 0; kb < 9; kb++) {
        int k0 = kb * 32;
        bf8_t ah0 = *(const bf8_t*)&lds_h[m * ASTR + k0 + quad * 8];
        bf8_t al0 = *(const bf8_t*)&lds_l[m * ASTR + k0 + quad * 8];
        bf8_t ah1 = *(const bf8_t*)&lds_h[(16 + m) * ASTR + k0 + quad * 8];
        bf8_t al1 = *(const bf8_t*)&lds_l[(16 + m) * ASTR + k0 + quad * 8];
#pragma unroll
        for (int ct = 0; ct < 4; ct++) {
            int nt = wv * 4 + ct;
            const bf8_t bh = *(const bf8_t*)&Wfh[(kb * 16 + nt) * 512 + lane * 8];
            const bf8_t bl = *(const bf8_t*)&Wfl[(kb * 16 + nt) * 512 + lane * 8];
            acc2[0][ct] = __builtin_amdgcn_mfma_f32_16x16x32_bf16(ah0, bh, acc2[0][ct], 0, 0, 0);
            acc2[0][ct] = __builtin_amdgcn_mfma_f32_16x16x32_bf16(al0, bh, acc2[0][ct], 0, 0, 0);
            acc2[0][ct] = __builtin_amdgcn_mfma_f32_16x16x32_bf16(ah0, bl, acc2[0][ct], 0, 0, 0);
            acc2[1][ct] = __builtin_amdgcn_mfma_f32_16x16x32_bf16(ah1, bh, acc2[1][ct], 0, 0, 0);
            acc2[1][ct] = __builtin_amdgcn_mfma_f32_16x16x32_bf16(al1, bh, acc2[1][ct], 0, 0, 0);
            acc2[1][ct] = __builtin_amdgcn_mfma_f32_16x16x32_bf16(ah1, bl, acc2[1][ct], 0, 0, 0);
        }
    }
#pragma unroll
    for (int rt = 0; rt < 2; rt++) {
#pragma unroll
        for (int r = 0; r < 4; r++) {
            int row = rows_s[rt * 16 + quad * 4 + r];
            if (row < 0) continue;
#pragma unroll
            for (int ct = 0; ct < 4; ct++) {
                int n = n0 + ct * 16 + m;
                out[(size_t)row * 256 + n] = f2bf(acc2[rt][ct][r] + bias[n]);
            }
        }
    }
}

// ----------------------------- misc -----------------------------

__global__ __launch_bounds__(256) void k_copy_rows(int layer) {
    int w = (blockIdx.x * blockDim.x + threadIdx.x) >> 5;
    int lane = threadIdx.x & 31;
    if (w >= g_cnt[layer]) return;
    int i = g_lists[layer * N_NODES + w];
    *(uint4*)(g_x + (size_t)i * 256 + lane * 8) =
        *(const uint4*)(g_pi + (size_t)i * 256 + lane * 8);
}

__global__ __launch_bounds__(256) void k_relu() {
    int i = blockIdx.x * blockDim.x + threadIdx.x;
    if (i >= N_NODES * 32) return;
    ushort4 a = ((ushort4*)g_x)[i * 2];
    ushort4 b = ((ushort4*)g_x)[i * 2 + 1];
    a.x = (a.x & 0x8000) ? 0 : a.x; a.y = (a.y & 0x8000) ? 0 : a.y;
    a.z = (a.z & 0x8000) ? 0 : a.z; a.w = (a.w & 0x8000) ? 0 : a.w;
    b.x = (b.x & 0x8000) ? 0 : b.x; b.y = (b.y & 0x8000) ? 0 : b.y;
    b.z = (b.z & 0x8000) ? 0 : b.z; b.w = (b.w & 0x8000) ? 0 : b.w;
    ((ushort4*)g_x)[i * 2] = a;
    ((ushort4*)g_x)[i * 2 + 1] = b;
}

__global__ __launch_bounds__(256) void k_pool(const int* __restrict__ batch) {
    __shared__ int bs[128];
    int i0 = blockIdx.x * 128;
    if (threadIdx.x < 128) {
        int i = i0 + threadIdx.x;
        bs[threadIdx.x] = (i < N_NODES) ? batch[i] : -1;
    }
    __syncthreads();
    int c = threadIdx.x;
    int lim = min(128, N_NODES - i0);
    float acc = 0.f;
    int cur = bs[0];
    for (int ii = 0; ii < lim; ii++) {
        int g = bs[ii];
        if (g != cur) { atomicAdd(&g_pooled[cur * 256 + c], acc); acc = 0.f; cur = g; }
        acc += fmaxf(bf2f(g_x[(size_t)(i0 + ii) * 256 + c]), 0.f);
    }
    atomicAdd(&g_pooled[cur * 256 + c], acc);
}

__global__ void k_final(const float* __restrict__ W_lin, const float* __restrict__ b_lin,
                        float* __restrict__ out) {
    int g = blockIdx.x;
    int lane = threadIdx.x;
    float4 p = *(const float4*)(g_pooled + g * 256 + lane * 4);
    float4 w = *(const float4*)(W_lin + lane * 4);
    float s = p.x * w.x + p.y * w.y + p.z * w.z + p.w * w.w;
    for (int o = 32; o > 0; o >>= 1) s += __shfl_down(s, o);
    if (lane == 0) out[g] = s + b_lin[0];
}

// ----------------------------- host -----------------------------

extern "C" void kernel_launch(void* const* d_in, const int* in_sizes, int n_in,
                              void* d_out, int out_size, void* d_ws, size_t ws_size,
                              hipStream_t stream) {
    const float* xin   = (const float*)d_in[0];
    const float* fs    = (const float*)d_in[1];
    const int* ei      = (const int*)d_in[2];
    const int* inner   = (const int*)d_in[3];
    const int* fwd     = (const int*)d_in[4];
    const int* layers  = (const int*)d_in[6];
    const int* batch   = (const int*)d_in[7];
    const float* W_up  = (const float*)d_in[8];
    const float* b_up  = (const float*)d_in[9];
    const float* W_in  = (const float*)d_in[10];
    const float* b_in  = (const float*)d_in[11];
    const float* W_fw  = (const float*)d_in[12];
    const float* b_fw  = (const float*)d_in[13];
    const float* W_lin = (const float*)d_in[14];
    const float* b_lin = (const float*)d_in[15];
    float* out = (float*)d_out;

    // --- CSR build + weight split + fs bf16 copy ---
    k_init<<<(NSETS * N_NODES + 255) / 256, 256, 0, stream>>>();
    k_fsb<<<(N_NODES * 32 + 255) / 256, 256, 0, stream>>>(fs);
    k_wt<<<(288 * 256 + 255) / 256, 256, 0, stream>>>(W_in, 0);
    k_wt<<<(288 * 256 + 255) / 256, 256, 0, stream>>>(W_fw, 1);
    k_count_all<<<(CSR_TOTAL - NE_SET + 255) / 256, 256, 0, stream>>>(ei, inner, fwd, layers);
    k_dinv<<<(NSETS * N_NODES + 255) / 256, 256, 0, stream>>>();
    k_scan_a<<<NSETS * NCHK, 256, 0, stream>>>();
    k_scan_b<<<1, 1024, 0, stream>>>();
    k_scan_c<<<NSETS * NCHK, 256, 0, stream>>>();
    k_fill_all<<<(CSR_TOTAL - NE_SET + 255) / 256, 256, 0, stream>>>(ei, inner, fwd, layers);
    k_lists<<<(N_NODES + 255) / 256, 256, 0, stream>>>(layers);

    // --- conv0 ---
    k_gather16<<<(N_NODES * 16 + 255) / 256, 256, 0, stream>>>(xin);
    k_gemm0<<<N_NODES / 8, 256, 0, stream>>>(W_up, b_up);

    auto conv = [&](int slot, int which, const float* bias, int layer, int topi) {
        k_conv<<<(N_NODES + 31) / 32, 256, 0, stream>>>(slot, which, bias, layer, topi);
    };

    for (int p = 0; p < NPROP; p++) {
        for (int il = 0; il < NLAYERS; il++) {
            if (il < NLAYERS - 1) {
                conv(1 + il, 0, b_in, il, 0);
                conv(5 + il, 1, b_fw, il + 1, 0);   // il=3 fwd is dead
            } else {
                conv(1 + il, 0, b_in, -1, 1);       // full -> pi
                k_copy_rows<<<12500, 256, 0, stream>>>(3);
            }
        }
        k_relu<<<(N_NODES * 32 + 255) / 256, 256, 0, stream>>>();
        for (int il = NLAYERS - 1; il >= 0; il--) {
            if (il >= 1) k_copy_rows<<<12500, 256, 0, stream>>>(il - 1);
            conv(1 + il, 0, b_in, il, 0);
        }
        if (p < NPROP - 1)
            k_relu<<<(N_NODES * 32 + 255) / 256, 256, 0, stream>>>();
    }

    k_pool<<<(N_NODES + 127) / 128, 256, 0, stream>>>(batch);
    k_final<<<NGRAPHS, 64, 0, stream>>>(W_lin, b_lin, out);
}